// Round 9
// baseline (3206.114 us; speedup 1.0000x reference)
//
#include <hip/hip_runtime.h>
#include <math.h>

#define B_  32
#define T_  64
#define TW_ 32
#define EW_ 300
#define H_  512
#define E_  1024
#define HH_ 512
#define C_  7
#define N_  2048   // B*T

typedef float f32x4 __attribute__((ext_vector_type(4)));
typedef short s16x8 __attribute__((ext_vector_type(8)));
typedef unsigned short u16;
typedef unsigned int u32;

__device__ __forceinline__ float sigm(float x){ return 1.f/(1.f+expf(-x)); }
__device__ __forceinline__ float bf2f(u16 u){
  union{float f; unsigned v;} x; x.v = ((unsigned)u)<<16; return x.f;
}
__device__ __forceinline__ u16 f2bf(float f){
  union{float f; unsigned v;} x; x.f = f;
  unsigned r = x.v + 0x7FFF + ((x.v>>16)&1);
  return (u16)(r>>16);
}
// async 16B global->LDS (dest: wave-uniform base + lane*16)
__device__ __forceinline__ void g2lds16(const void* g, void* l){
  __builtin_amdgcn_global_load_lds((const __attribute__((address_space(1))) u32*)g,
                                   (__attribute__((address_space(3))) u32*)l, 16, 0, 0);
}

// ===========================================================================
// Pre-pass packing kernels (verified R8)
// ===========================================================================
// Wpk[pan(32)][kc(26)][row(128)=g*32+ml][32], R = g*512 + mt*32 + ml
__global__ __launch_bounds__(256) void k_pack_w(
    const float* __restrict__ Wih_f, const float* __restrict__ Whh_f,
    const float* __restrict__ Wih_b, const float* __restrict__ Whh_b,
    u16* __restrict__ Wpk)
{
  size_t idx = (size_t)blockIdx.x*256 + threadIdx.x;
  if(idx >= (size_t)32*26*4096) return;
  int c   = (int)(idx & 31);
  int row = (int)((idx >> 5) & 127);
  int kc  = (int)((idx >> 12) % 26);
  int pan = (int)(idx / ((size_t)26*4096));
  int dir = pan >> 4, mt = pan & 15;
  int g = row >> 5, ml = row & 31;
  int R = g*512 + mt*32 + ml;
  int k = kc*32 + c;
  const float* Wih = dir ? Wih_b : Wih_f;
  const float* Whh = dir ? Whh_b : Whh_f;
  float v = (k < 320) ? ((k < EW_) ? Wih[(size_t)R*EW_ + k] : 0.f)
                      : Whh[(size_t)R*H_ + (k-320)];
  Wpk[idx] = f2bf(v);
}

// xpk[wt(32)][nt(32)][kc(10)][row(64)][32]; n = nt*64+row, k = kc*32+c
__global__ __launch_bounds__(256) void k_pack_x(
    const float* __restrict__ input, u16* __restrict__ xpk)
{
  size_t idx = (size_t)blockIdx.x*256 + threadIdx.x;
  if(idx >= (size_t)32*32*10*2048) return;
  int c   = (int)(idx & 31);
  int row = (int)((idx >> 5) & 63);
  int kc  = (int)((idx >> 11) % 10);
  int q2  = (int)((idx >> 11) / 10);      // wt*32+nt
  int nt  = q2 & 31, wt = q2 >> 5;
  int n = nt*64 + row;
  int k = kc*32 + c;
  float v = (k < EW_) ? input[((size_t)n*TW_ + wt)*EW_ + k] : 0.f;
  xpk[idx] = f2bf(v);
}

__global__ __launch_bounds__(256) void k_f2bf(const float* __restrict__ src,
                                              u16* __restrict__ dst, int n)
{
  int idx = blockIdx.x*256 + threadIdx.x;
  if(idx < n) dst[idx] = f2bf(src[idx]);
}

__global__ __launch_bounds__(256) void k_wattT(const float* __restrict__ W,
                                               u16* __restrict__ dst)
{
  int idx = blockIdx.x*256 + threadIdx.x;
  if(idx >= E_*E_) return;
  int j = idx >> 10, k = idx & 1023;
  dst[idx] = f2bf(W[(size_t)k*E_ + j]);   // dst[j][k] = W[k][j]
}

// ===========================================================================
// Phase 1 R9: NO-LDS, NO-BARRIER BiLSTM step. Packed layouts make every MFMA
// fragment a contiguous 1KB per wave -> direct global->VGPR coalesced loads.
// Each wave is an independent DMA+MFMA stream (max wave slip, compiler vmcnt
// pipelining across the fully-unrolled 26 chunks; all loads independent).
// grid (32 panels, 32 nt) = 1024 blocks (4/CU), 256 thr.
// c stored packed per-block [64][32] fp32 (layout-only change).
// ===========================================================================
__global__ __launch_bounds__(256, 4) void lstm5(
    const u16* __restrict__ xpk, const u16* __restrict__ Wpk,
    const float* __restrict__ b_f, const float* __restrict__ b_b,
    const u16* __restrict__ hpk_in, u16* __restrict__ hpk_out,
    float* __restrict__ cpk, u16* __restrict__ featsbf, int t)
{
  const int panel = blockIdx.x, nt = blockIdx.y;
  const int dir = panel & 1, mt = panel >> 1;
  const int wt = dir ? (TW_-1-t) : t;
  const u16* srcW = Wpk + (size_t)(dir*16+mt)*26*4096;
  const u16* srcX = xpk + (size_t)(wt*32+nt)*10*2048;
  const u16* srcH = hpk_in + (size_t)(dir*32+nt)*16*2048;

  const int tid = threadIdx.x;
  const int w = tid >> 6, l = tid & 63;
  const int lr = l & 15, lh = l >> 4;
  const int wn = w >> 1, wm = w & 1;

  // per-lane element offsets (u16 units) within a chunk block
  const int aoff0 = (wn*32 +  0 + lr)*32 + lh*8;
  const int aoff1 = (wn*32 + 16 + lr)*32 + lh*8;
  const int boffb = (wm*16 + lr)*32 + lh*8;     // + g*1024

  f32x4 acc[2][4];
  #pragma unroll
  for(int a=0;a<2;a++)
    #pragma unroll
    for(int g=0;g<4;g++) acc[a][g] = (f32x4){0.f,0.f,0.f,0.f};

  #pragma unroll
  for(int kc=0; kc<26; ++kc){
    const u16* aB = (kc < 10) ? (srcX + (size_t)kc*2048) : (srcH + (size_t)(kc-10)*2048);
    const u16* bB = srcW + (size_t)kc*4096;
    s16x8 av0 = *(const s16x8*)&aB[aoff0];
    s16x8 av1 = *(const s16x8*)&aB[aoff1];
    s16x8 bv0 = *(const s16x8*)&bB[boffb];
    s16x8 bv1 = *(const s16x8*)&bB[boffb + 1024];
    s16x8 bv2 = *(const s16x8*)&bB[boffb + 2048];
    s16x8 bv3 = *(const s16x8*)&bB[boffb + 3072];
    acc[0][0] = __builtin_amdgcn_mfma_f32_16x16x32_bf16(av0, bv0, acc[0][0], 0,0,0);
    acc[0][1] = __builtin_amdgcn_mfma_f32_16x16x32_bf16(av0, bv1, acc[0][1], 0,0,0);
    acc[0][2] = __builtin_amdgcn_mfma_f32_16x16x32_bf16(av0, bv2, acc[0][2], 0,0,0);
    acc[0][3] = __builtin_amdgcn_mfma_f32_16x16x32_bf16(av0, bv3, acc[0][3], 0,0,0);
    acc[1][0] = __builtin_amdgcn_mfma_f32_16x16x32_bf16(av1, bv0, acc[1][0], 0,0,0);
    acc[1][1] = __builtin_amdgcn_mfma_f32_16x16x32_bf16(av1, bv1, acc[1][1], 0,0,0);
    acc[1][2] = __builtin_amdgcn_mfma_f32_16x16x32_bf16(av1, bv2, acc[1][2], 0,0,0);
    acc[1][3] = __builtin_amdgcn_mfma_f32_16x16x32_bf16(av1, bv3, acc[1][3], 0,0,0);
  }

  // ---- cell update epilogue; c and h in packed block-owned tiles ----
  const float* bias = dir ? b_b : b_f;
  const int col = wm*16 + lr;                  // m-local in [0,32)
  const int m = mt*32 + col;                   // dir-local m in [0,512)
  const float bi = bias[m], bfv = bias[H_+m], bg = bias[2*H_+m], bo = bias[3*H_+m];
  float* cp = cpk + ((size_t)(dir*32+nt)*16 + mt)*2048;
  u16* hop = hpk_out + ((size_t)(dir*32+nt)*16 + mt)*2048;
  const int n0 = nt*64;
  #pragma unroll
  for(int nf=0; nf<2; ++nf){
    #pragma unroll
    for(int r=0; r<4; ++r){
      const int row = wn*32 + nf*16 + lh*4 + r;
      float gi = acc[nf][0][r] + bi;
      float gf = acc[nf][1][r] + bfv;
      float gc = acc[nf][2][r] + bg;
      float go = acc[nf][3][r] + bo;
      float c_old = cp[row*32 + col];
      float c2 = sigm(gf)*c_old + sigm(gi)*tanhf(gc);
      float h2 = sigm(go)*tanhf(c2);
      cp[row*32 + col] = c2;
      if(t == TW_-1) featsbf[(size_t)(n0+row)*E_ + dir*H_ + m] = f2bf(h2);
      else           hop[row*32 + col] = f2bf(h2);
    }
  }
}

// ===========================================================================
// q = feats @ W_att  (one-time, bf16 MFMA, fp32 out)  [verified]
// ===========================================================================
__global__ __launch_bounds__(256) void k_qgemm(const u16* __restrict__ featsbf,
                                               const u16* __restrict__ WattT,
                                               float* __restrict__ q)
{
  const int n0 = blockIdx.x*64, j0 = blockIdx.y*64;
  __shared__ __align__(16) u16 As[64*40];
  __shared__ __align__(16) u16 Bs[64*40];
  const int tid = threadIdx.x;
  const int w = tid>>6, l = tid&63, lr = l&15, lk = (l>>4)*8;
  const int arow = tid>>2, ak8 = (tid&3)*8;

  f32x4 acc[4];
  #pragma unroll
  for(int i=0;i<4;i++) acc[i] = (f32x4){0.f,0.f,0.f,0.f};

  for(int kc=0; kc<32; ++kc){
    *(s16x8*)&As[arow*40 + ak8] = *(const s16x8*)&featsbf[(size_t)(n0+arow)*E_ + kc*32 + ak8];
    *(s16x8*)&Bs[arow*40 + ak8] = *(const s16x8*)&WattT[(size_t)(j0+arow)*E_ + kc*32 + ak8];
    __syncthreads();
    s16x8 av = *(const s16x8*)&As[(w*16 + lr)*40 + lk];
    #pragma unroll
    for(int mf=0; mf<4; ++mf){
      s16x8 bv = *(const s16x8*)&Bs[(mf*16 + lr)*40 + lk];
      acc[mf] = __builtin_amdgcn_mfma_f32_16x16x32_bf16(av, bv, acc[mf], 0,0,0);
    }
    __syncthreads();
  }
  #pragma unroll
  for(int mf=0; mf<4; ++mf)
    #pragma unroll
    for(int r=0; r<4; ++r){
      int n = n0 + w*16 + (l>>4)*4 + r;
      q[(size_t)n*E_ + j0 + mf*16 + lr] = acc[mf][r];
    }
}

// ===========================================================================
// Phase 2 building blocks  [unchanged - verified correct R4-R8]
// ===========================================================================
struct GArg2 {
  const u16* xA; const u16* xB;
  long ldA; long ldB;
  const u16* W; int K;
};

__device__ __forceinline__ void gemm32v2(const GArg2 a, int R, int xt, int ks,
                                         int KS, int z, float* __restrict__ part,
                                         char* smem)
{
  u16* Xs0 = (u16*)smem;
  u16* Xs1 = Xs0 + 32*40;
  u16* Ws0 = Xs1 + 32*40;
  u16* Ws1 = Ws0 + 128*32;
  const int Kc = a.K / KS;
  const int nch = Kc >> 5;
  const int kb0 = ks * Kc;
  const int tid = threadIdx.x;
  const int w = tid>>6, l = tid&63, lr = l&15, lh = l>>4;

  f32x4 a00={0,0,0,0}, a01={0,0,0,0}, a10={0,0,0,0}, a11={0,0,0,0};

  auto issueW = [&](int c, u16* Wb){
    const int kb = kb0 + c*32;
    #pragma unroll
    for(int c2=0;c2<2;++c2){
      const int cc = w*2 + c2;
      const char* g = (const char*)(a.W + (size_t)(xt*128 + cc*16 + (l>>2))*a.K + kb) + (l&3)*16;
      g2lds16(g, (char*)Wb + cc*1024);
    }
  };
  auto loadX = [&](int c, short4* xr){
    const int kb = kb0 + c*32;
    const int row = tid>>3, k4 = (tid&7)*4;
    short4 xv = *(const short4*)&a.xA[(size_t)row*a.ldA + kb + k4];
    if(a.xB){
      short4 yv = *(const short4*)&a.xB[(size_t)row*a.ldB + kb + k4];
      xv.x = (short)f2bf(bf2f((u16)xv.x)+bf2f((u16)yv.x));
      xv.y = (short)f2bf(bf2f((u16)xv.y)+bf2f((u16)yv.y));
      xv.z = (short)f2bf(bf2f((u16)xv.z)+bf2f((u16)yv.z));
      xv.w = (short)f2bf(bf2f((u16)xv.w)+bf2f((u16)yv.w));
    }
    *xr = xv;
  };
  auto writeX = [&](short4 xv, u16* Xb){
    *(short4*)&Xb[(tid>>3)*40 + (tid&7)*4] = xv;
  };

  short4 xr;
  issueW(0, Ws0); loadX(0, &xr); writeX(xr, Xs0);
  __syncthreads();
  for(int c=0;c<nch;++c){
    u16* Xc = (c&1)?Xs1:Xs0; u16* Wc = (c&1)?Ws1:Ws0;
    u16* Xn = (c&1)?Xs0:Xs1; u16* Wn = (c&1)?Ws0:Ws1;
    const bool pre = (c+1 < nch);
    if(pre){ issueW(c+1, Wn); loadX(c+1, &xr); }
    s16x8 av0 = *(const s16x8*)&Xc[lr*40 + lh*8];
    s16x8 av1 = *(const s16x8*)&Xc[(16+lr)*40 + lh*8];
    s16x8 bv0 = *(const s16x8*)&Wc[(w*32 + lr)*32 + lh*8];
    s16x8 bv1 = *(const s16x8*)&Wc[(w*32 + 16 + lr)*32 + lh*8];
    a00 = __builtin_amdgcn_mfma_f32_16x16x32_bf16(av0, bv0, a00, 0,0,0);
    a01 = __builtin_amdgcn_mfma_f32_16x16x32_bf16(av0, bv1, a01, 0,0,0);
    a10 = __builtin_amdgcn_mfma_f32_16x16x32_bf16(av1, bv0, a10, 0,0,0);
    a11 = __builtin_amdgcn_mfma_f32_16x16x32_bf16(av1, bv1, a11, 0,0,0);
    if(pre) writeX(xr, Xn);
    __syncthreads();
  }
  float* dst = part + (size_t)((z*KS + ks)*B_)*R + xt*128 + w*32;
  f32x4 accs[2][2] = {{a00,a01},{a10,a11}};
  #pragma unroll
  for(int nf=0; nf<2; ++nf)
    #pragma unroll
    for(int mf=0; mf<2; ++mf)
      #pragma unroll
      for(int r=0; r<4; ++r){
        int n = nf*16 + lh*4 + r;
        dst[(size_t)n*R + mf*16 + lr] = accs[nf][mf][r];
      }
}

__device__ __forceinline__ void att_body(const float* __restrict__ q,
                                         const u16* __restrict__ histbf,
                                         const u16* __restrict__ featsbf,
                                         u16* __restrict__ xcbf,
                                         int i, int b, char* smem)
{
  float* qs = (float*)smem;      // 1024
  float* sc = qs + E_;           // 64
  const int tid = threadIdx.x;
  *(float4*)&qs[tid*4] = *(const float4*)&q[((size_t)b*T_ + i)*E_ + tid*4];
  __syncthreads();
  const int wv = tid>>6, ln = tid&63;
  for(int L = wv; L <= i; L += 4){
    const u16* hl = histbf + ((size_t)L*B_ + b)*E_;
    float s = 0.f;
    s16x8 h0 = *(const s16x8*)&hl[ln*16];
    s16x8 h1 = *(const s16x8*)&hl[ln*16 + 8];
    #pragma unroll
    for(int j=0;j<8;j++){
      s += qs[ln*16 + j]     * bf2f((u16)h0[j]);
      s += qs[ln*16 + 8 + j] * bf2f((u16)h1[j]);
    }
    #pragma unroll
    for(int off=32; off; off>>=1) s += __shfl_down(s, off);
    if(ln == 0) sc[L] = s;
  }
  __syncthreads();
  if(tid < 64){
    float v  = (tid <= i) ? sc[tid] : -INFINITY;
    float mx = v;
    #pragma unroll
    for(int off=32; off; off>>=1) mx = fmaxf(mx, __shfl_xor(mx, off));
    float ex = (tid <= i) ? expf(v - mx) : 0.f;
    float sm = ex;
    #pragma unroll
    for(int off=32; off; off>>=1) sm += __shfl_xor(sm, off);
    sc[tid] = ex / sm;
  }
  __syncthreads();
  const int e4 = tid*4;
  float c0=0.f, c1=0.f, c2=0.f, c3=0.f;
  for(int L=0; L<=i; ++L){
    float wl = sc[L];
    short4 hv = *(const short4*)&histbf[((size_t)L*B_ + b)*E_ + e4];
    c0 += wl*bf2f((u16)hv.x);
    c1 += wl*bf2f((u16)hv.y);
    c2 += wl*bf2f((u16)hv.z);
    c3 += wl*bf2f((u16)hv.w);
  }
  const u16* xi = featsbf + ((size_t)b*T_ + i)*E_ + e4;
  xcbf[(size_t)b*E_ + e4 + 0] = f2bf(bf2f(xi[0]) + c0);
  xcbf[(size_t)b*E_ + e4 + 1] = f2bf(bf2f(xi[1]) + c1);
  xcbf[(size_t)b*E_ + e4 + 2] = f2bf(bf2f(xi[2]) + c2);
  xcbf[(size_t)b*E_ + e4 + 3] = f2bf(bf2f(xi[3]) + c3);
}

__device__ __forceinline__ void gru_comb(const float* __restrict__ part, int R, int J, int KS,
                                         const float* __restrict__ bih, const float* __restrict__ bhh,
                                         const float* __restrict__ hprev_f,
                                         float* __restrict__ dst_f,
                                         u16* __restrict__ dstbf,
                                         float* __restrict__ dst_seq, int idx)
{
  const int b = idx / J, e = idx - b*J;
  float ir=0.f, iz=0.f, in_=0.f, hr=0.f, hz=0.f, hn=0.f;
  for(int ks=0; ks<KS; ++ks){
    const float* p0 = part + (size_t)(ks*B_ + b)*R;
    const float* p1 = part + (size_t)((KS+ks)*B_ + b)*R;
    ir += p0[e]; iz += p0[J+e]; in_ += p0[2*J+e];
    hr += p1[e]; hz += p1[J+e]; hn  += p1[2*J+e];
  }
  ir += bih[e]; iz += bih[J+e]; in_ += bih[2*J+e];
  hr += bhh[e]; hz += bhh[J+e]; hn  += bhh[2*J+e];
  const float r = sigm(ir + hr);
  const float z = sigm(iz + hz);
  const float n = tanhf(in_ + r*hn);
  const float hp = hprev_f[(size_t)b*J + e];
  const float h2 = (1.f - z)*n + z*hp;
  dst_f[(size_t)b*J + e] = h2;
  dstbf[(size_t)b*J + e] = f2bf(h2);
  if(dst_seq) dst_seq[(size_t)b*J + e] = h2;
}

// A(i): g-gemm(i) [384] | e-gemm(i-1) [192] | att(i) [32]   grid 608
__global__ __launch_bounds__(256) void k_A(GArg2 g0, GArg2 g1, GArg2 e0, GArg2 e1,
    float* __restrict__ part_g, float* __restrict__ part_e,
    const float* __restrict__ q, const u16* __restrict__ histbf,
    const u16* __restrict__ featsbf, u16* __restrict__ xcbf, int i)
{
  __shared__ __align__(16) char smem[21504];
  const int x = blockIdx.x;
  if(x < 384){
    if(i >= T_) return;
    const int xt = x % 24, ks = (x/24) & 7, z = x/192;
    gemm32v2(z ? g1 : g0, 3*E_, xt, ks, 8, z, part_g, smem);
  } else if(x < 576){
    if(i < 1) return;
    const int ix = x-384, xt = ix % 12, ks = (ix/12) & 7, z = ix/96;
    gemm32v2(z ? e1 : e0, 3*HH_, xt, ks, 8, z, part_e, smem);
  } else {
    if(i >= T_) return;
    att_body(q, histbf, featsbf, xcbf, i, x-576, smem);
  }
}

// B(i): g-comb(i) [128] | p-gemm(i) [384] | e-comb(i-1) [64]   grid 576
__global__ __launch_bounds__(256) void k_B(GArg2 p0, GArg2 p1,
    const float* __restrict__ part_g, const float* __restrict__ part_e,
    const float* __restrict__ g_bih, const float* __restrict__ g_bhh,
    const float* __restrict__ e_bih, const float* __restrict__ e_bhh,
    const float* __restrict__ gf_prev, float* __restrict__ gf_next,
    u16* __restrict__ histbf,
    float* __restrict__ emof, u16* __restrict__ emobf,
    float* __restrict__ emo_seq, float* __restrict__ part_p, int i)
{
  __shared__ __align__(16) char smem[21504];
  const int x = blockIdx.x;
  if(x < 128){
    if(i >= T_) return;
    gru_comb(part_g, 3*E_, E_, 8, g_bih, g_bhh,
             gf_prev, gf_next, histbf + (size_t)(i+1)*B_*E_, nullptr,
             x*256 + (int)threadIdx.x);
  } else if(x < 512){
    if(i >= T_) return;
    const int ix = x-128, xt = ix % 24, ks = (ix/24) & 7, z = ix/192;
    gemm32v2(z ? p1 : p0, 3*E_, xt, ks, 8, z, part_p, smem);
  } else {
    if(i < 1) return;
    gru_comb(part_e, 3*HH_, HH_, 8, e_bih, e_bhh,
             emof, emof, emobf, emo_seq + (size_t)(i-1)*B_*HH_,
             (x-512)*256 + (int)threadIdx.x);
  }
}

// C(i): p-comb(i)   grid 128
__global__ __launch_bounds__(256) void k_C(const float* __restrict__ part_p,
    const float* __restrict__ p_bih, const float* __restrict__ p_bhh,
    float* __restrict__ partyf_p, u16* __restrict__ partybf_p)
{
  const int idx = blockIdx.x*256 + threadIdx.x;
  gru_comb(part_p, 3*E_, E_, 8, p_bih, p_bhh, partyf_p, partyf_p, partybf_p, nullptr, idx);
}

// classifier
__global__ __launch_bounds__(256) void classify(const float* __restrict__ emo_seq,
    const float* __restrict__ clsW, const float* __restrict__ clsb, float* __restrict__ out)
{
  const int idx = blockIdx.x*256 + threadIdx.x;
  if(idx >= B_*T_*C_) return;
  const int c = idx % C_;
  const int bt = idx / C_;
  const int t = bt % T_, b = bt / T_;
  const float* e = emo_seq + (size_t)(t*B_ + b)*HH_;
  const float* w = clsW + (size_t)c*HH_;
  float s = clsb[c];
  for(int h=0; h<HH_; ++h) s += e[h]*w[h];
  out[idx] = s;
}

// ===========================================================================
extern "C" void kernel_launch(void* const* d_in, const int* in_sizes, int n_in,
                              void* d_out, int out_size, void* d_ws, size_t ws_size,
                              hipStream_t stream)
{
  const float* input  = (const float*)d_in[0];
  const float* Wih_f  = (const float*)d_in[1];
  const float* Whh_f  = (const float*)d_in[2];
  const float* b_f    = (const float*)d_in[3];
  const float* Wih_b  = (const float*)d_in[4];
  const float* Whh_b  = (const float*)d_in[5];
  const float* b_b    = (const float*)d_in[6];
  const float* W_att  = (const float*)d_in[7];
  const float* g_Wih  = (const float*)d_in[8];
  const float* g_Whh  = (const float*)d_in[9];
  const float* g_bih  = (const float*)d_in[10];
  const float* g_bhh  = (const float*)d_in[11];
  const float* p_Wih  = (const float*)d_in[12];
  const float* p_Whh  = (const float*)d_in[13];
  const float* p_bih  = (const float*)d_in[14];
  const float* p_bhh  = (const float*)d_in[15];
  const float* e_Wih  = (const float*)d_in[16];
  const float* e_Whh  = (const float*)d_in[17];
  const float* e_bih  = (const float*)d_in[18];
  const float* e_bhh  = (const float*)d_in[19];
  const float* cls_W  = (const float*)d_in[20];
  const float* cls_b  = (const float*)d_in[21];

  // ---- workspace layout ----
  char* base = (char*)d_ws;
  size_t off = 0;
  auto alloc = [&](size_t bytes)->char*{
    char* p = base + off; off += (bytes + 255) & ~(size_t)255; return p;
  };
  u16*   Wpk     = (u16*)alloc((size_t)32*26*4096*2);       // 6.8 MB
  u16*   xpk     = (u16*)alloc((size_t)32*32*10*2048*2);    // 41.9 MB (phase1 only)
  u16*   hpkA    = (u16*)alloc((size_t)2*32*16*2048*2);     // 4.19 MB (phase1 only)
  u16*   hpkB    = (u16*)alloc((size_t)2*32*16*2048*2);     // 4.19 MB (phase1 only, adjacent)
  float* cpk     = (float*)alloc((size_t)2*32*16*2048*4);   // 8.39 MB (phase1 only, packed)
  u16*   featsbf = (u16*)alloc((size_t)N_*E_*2);
  u16*   eWih    = (u16*)alloc((size_t)3*HH_*E_*2);
  u16*   eWhh    = (u16*)alloc((size_t)3*HH_*HH_*2);
  u16*   histbf  = (u16*)alloc((size_t)(T_+1)*B_*E_*2);
  float* gfbuf   = (float*)alloc((size_t)2*B_*E_*4);
  float* partyf  = (float*)alloc((size_t)2*B_*E_*4);
  u16*   partybf = (u16*)alloc((size_t)2*B_*E_*2);
  float* emof    = (float*)alloc((size_t)B_*HH_*4);
  u16*   emobf   = (u16*)alloc((size_t)B_*HH_*2);
  float* emo_seq = (float*)alloc((size_t)T_*B_*HH_*4);
  u16*   xcbf    = (u16*)alloc((size_t)B_*E_*2);
  float* part_p  = (float*)alloc((size_t)16*B_*3*E_*4);     // 6.29 MB
  // phase-2 buffers aliased into phase-1-only regions:
  u16*   gWih    = (u16*)((char*)xpk + 0);                  // 6.29 MB
  u16*   gWhh    = (u16*)((char*)xpk + 6291456);            // 6.29 MB
  u16*   pWih    = (u16*)((char*)xpk + 12582912);           // 6.29 MB
  u16*   pWhh    = (u16*)((char*)xpk + 18874368);           // 6.29 MB
  float* part_e  = (float*)((char*)xpk + 25165824);         // 3.15 MB
  float* q       = (float*)((char*)xpk + 28311552);         // 8.39 MB
  u16*   WattT   = (u16*)((char*)xpk + 36700160);           // 2.10 MB (ends 38.8 <= 41.9)
  float* part_g  = (float*)hpkA;                            // 6.29 <= 8.39 MB (hpkA+hpkB)

  // ---- zero-init ----
  hipMemsetAsync(hpkA,    0, (size_t)2*32*16*2048*2, stream);
  hipMemsetAsync(cpk,     0, (size_t)2*32*16*2048*4, stream);
  hipMemsetAsync(histbf,  0, (size_t)B_*E_*2, stream);        // slice 0
  hipMemsetAsync(gfbuf,   0, (size_t)B_*E_*4, stream);        // slice 0
  hipMemsetAsync(partyf,  0, (size_t)2*B_*E_*4, stream);
  hipMemsetAsync(partybf, 0, (size_t)2*B_*E_*2, stream);
  hipMemsetAsync(emof,    0, (size_t)B_*HH_*4, stream);
  hipMemsetAsync(emobf,   0, (size_t)B_*HH_*2, stream);

  // ---- pre-pass packing (phase 1 inputs) ----
  k_pack_w<<<dim3(((size_t)32*26*4096 + 255)/256), 256, 0, stream>>>(Wih_f, Whh_f, Wih_b, Whh_b, Wpk);
  k_pack_x<<<dim3(((size_t)32*32*10*2048 + 255)/256), 256, 0, stream>>>(input, xpk);

  // ---- Phase 1: BiLSTM, no-LDS no-barrier streaming kernel per step ----
  for(int t=0; t<TW_; ++t){
    u16* hin  = (t & 1) ? hpkB : hpkA;
    u16* hout = (t & 1) ? hpkA : hpkB;
    lstm5<<<dim3(32, 32), 256, 0, stream>>>(xpk, Wpk, b_f, b_b, hin, hout, cpk, featsbf, t);
  }

  // ---- phase-2 weight conversions (AFTER phase 1: they alias xpk) ----
  k_f2bf<<<dim3((3*E_*E_+255)/256), 256, 0, stream>>>(g_Wih, gWih, 3*E_*E_);
  k_f2bf<<<dim3((3*E_*E_+255)/256), 256, 0, stream>>>(g_Whh, gWhh, 3*E_*E_);
  k_f2bf<<<dim3((3*E_*E_+255)/256), 256, 0, stream>>>(p_Wih, pWih, 3*E_*E_);
  k_f2bf<<<dim3((3*E_*E_+255)/256), 256, 0, stream>>>(p_Whh, pWhh, 3*E_*E_);
  k_f2bf<<<dim3((3*HH_*E_+255)/256), 256, 0, stream>>>(e_Wih, eWih, 3*HH_*E_);
  k_f2bf<<<dim3((3*HH_*HH_+255)/256), 256, 0, stream>>>(e_Whh, eWhh, 3*HH_*HH_);
  k_wattT<<<dim3((E_*E_+255)/256), 256, 0, stream>>>(W_att, WattT);

  // ---- q = feats @ W_att ----
  k_qgemm<<<dim3(32, 16), 256, 0, stream>>>(featsbf, WattT, q);

  // ---- Phase 2: 3 launches/step ----
  for(int i=0; i<=T_; ++i){
    const int p  = i & 1;
    const int pe = (i-1) & 1;
    GArg2 ga0{ featsbf + (size_t)i*E_, partybf + (size_t)p*B_*E_, (long)T_*E_, (long)E_, gWih, E_ };
    GArg2 ga1{ histbf + (size_t)i*B_*E_, nullptr, (long)E_, 0, gWhh, E_ };
    GArg2 ea0{ partybf + (size_t)pe*B_*E_, nullptr, (long)E_, 0, eWih, E_ };
    GArg2 ea1{ emobf, nullptr, (long)HH_, 0, eWhh, HH_ };
    k_A<<<dim3(608), 256, 0, stream>>>(ga0, ga1, ea0, ea1, part_g, part_e,
                                       q, histbf, featsbf, xcbf, i);
    GArg2 pa0{ xcbf, nullptr, (long)E_, 0, pWih, E_ };
    GArg2 pa1{ partybf + (size_t)p*B_*E_, nullptr, (long)E_, 0, pWhh, E_ };
    k_B<<<dim3(576), 256, 0, stream>>>(pa0, pa1, part_g, part_e,
                                       g_bih, g_bhh, e_bih, e_bhh,
                                       gfbuf + (size_t)(i&1)*B_*E_,
                                       gfbuf + (size_t)((i+1)&1)*B_*E_,
                                       histbf, emof, emobf, emo_seq, part_p, i);
    if(i < T_){
      k_C<<<dim3(128), 256, 0, stream>>>(part_p, p_bih, p_bhh,
                                         partyf + (size_t)p*B_*E_,
                                         partybf + (size_t)p*B_*E_);
    }
  }

  // ---- classifier ----
  classify<<<dim3((B_*T_*C_+255)/256), 256, 0, stream>>>(emo_seq, cls_W, cls_b, (float*)d_out);
}

// Round 10
// 2444.122 us; speedup vs baseline: 1.3118x; 1.3118x over previous
//
#include <hip/hip_runtime.h>
#include <math.h>

#define B_  32
#define T_  64
#define TW_ 32
#define EW_ 300
#define H_  512
#define E_  1024
#define HH_ 512
#define C_  7
#define N_  2048   // B*T

typedef float f32x4 __attribute__((ext_vector_type(4)));
typedef short s16x8 __attribute__((ext_vector_type(8)));
typedef unsigned short u16;
typedef unsigned int u32;

__device__ __forceinline__ float sigm(float x){ return 1.f/(1.f+expf(-x)); }
__device__ __forceinline__ float bf2f(u16 u){
  union{float f; unsigned v;} x; x.v = ((unsigned)u)<<16; return x.f;
}
__device__ __forceinline__ u16 f2bf(float f){
  union{float f; unsigned v;} x; x.f = f;
  unsigned r = x.v + 0x7FFF + ((x.v>>16)&1);
  return (u16)(r>>16);
}
// async 16B global->LDS (dest: wave-uniform base + lane*16)
__device__ __forceinline__ void g2lds16(const void* g, void* l){
  __builtin_amdgcn_global_load_lds((const __attribute__((address_space(1))) u32*)g,
                                   (__attribute__((address_space(3))) u32*)l, 16, 0, 0);
}

// ===========================================================================
// Pre-pass packing kernels
// ===========================================================================
// Wpk2[pan(64)=dir*32+ms][kc(26)][row(64)=g*16+ml][32], R = g*512 + ms*16 + ml
__global__ __launch_bounds__(256) void k_pack_w(
    const float* __restrict__ Wih_f, const float* __restrict__ Whh_f,
    const float* __restrict__ Wih_b, const float* __restrict__ Whh_b,
    u16* __restrict__ Wpk2)
{
  size_t idx = (size_t)blockIdx.x*256 + threadIdx.x;
  if(idx >= (size_t)64*26*2048) return;
  int c   = (int)(idx & 31);
  int row = (int)((idx >> 5) & 63);
  int kc  = (int)((idx >> 11) % 26);
  int pan = (int)(idx / ((size_t)26*2048));
  int dir = pan >> 5, ms = pan & 31;
  int g = row >> 4, ml = row & 15;
  int R = g*512 + ms*16 + ml;
  int k = kc*32 + c;
  const float* Wih = dir ? Wih_b : Wih_f;
  const float* Whh = dir ? Whh_b : Whh_f;
  float v = (k < 320) ? ((k < EW_) ? Wih[(size_t)R*EW_ + k] : 0.f)
                      : Whh[(size_t)R*H_ + (k-320)];
  Wpk2[idx] = f2bf(v);
}

// xpk[wt(32)][nt(32)][kc(10)][row(64)][32]; n = nt*64+row, k = kc*32+c  (R8, verified)
__global__ __launch_bounds__(256) void k_pack_x(
    const float* __restrict__ input, u16* __restrict__ xpk)
{
  size_t idx = (size_t)blockIdx.x*256 + threadIdx.x;
  if(idx >= (size_t)32*32*10*2048) return;
  int c   = (int)(idx & 31);
  int row = (int)((idx >> 5) & 63);
  int kc  = (int)((idx >> 11) % 10);
  int q2  = (int)((idx >> 11) / 10);      // wt*32+nt
  int nt  = q2 & 31, wt = q2 >> 5;
  int n = nt*64 + row;
  int k = kc*32 + c;
  float v = (k < EW_) ? input[((size_t)n*TW_ + wt)*EW_ + k] : 0.f;
  xpk[idx] = f2bf(v);
}

__global__ __launch_bounds__(256) void k_f2bf(const float* __restrict__ src,
                                              u16* __restrict__ dst, int n)
{
  int idx = blockIdx.x*256 + threadIdx.x;
  if(idx < n) dst[idx] = f2bf(src[idx]);
}

__global__ __launch_bounds__(256) void k_wattT(const float* __restrict__ W,
                                               u16* __restrict__ dst)
{
  int idx = blockIdx.x*256 + threadIdx.x;
  if(idx >= E_*E_) return;
  int j = idx >> 10, k = idx & 1023;
  dst[idx] = f2bf(W[(size_t)k*E_ + j]);   // dst[j][k] = W[k][j]
}

// ===========================================================================
// Phase 1 R10: 64n x 64gc tiles (4 gates x 16m), 3-buffer LDS (24KB ->
// 6 blocks/CU = 24 waves/CU), uniform 2 DMA/wave/chunk -> exact vmcnt(2).
// grid (64 panels = dir+2*ms, 32 nt) = 2048 blocks. Wave w owns 16 n-rows.
// h and c in packed block-private tiles (race-free).
// ===========================================================================
__global__ __launch_bounds__(256, 6) void lstm6(
    const u16* __restrict__ xpk, const u16* __restrict__ Wpk2,
    const float* __restrict__ b_f, const float* __restrict__ b_b,
    const u16* __restrict__ hpk_in, u16* __restrict__ hpk_out,
    float* __restrict__ cpk, u16* __restrict__ featsbf, int t)
{
  const int pan = blockIdx.x, nt = blockIdx.y;
  const int dir = pan & 1, ms = pan >> 1;          // ms: 16-col m-slice, 0..31
  const int wt = dir ? (TW_-1-t) : t;
  const u16* srcW = Wpk2 + (size_t)(dir*32+ms)*26*2048;
  const u16* srcX = xpk + (size_t)(wt*32+nt)*10*2048;
  const u16* srcH = hpk_in + (size_t)(dir*32+nt)*16*2048;

  __shared__ __align__(16) u16 As[3][2048];   // 4KB: 64n x 32k
  __shared__ __align__(16) u16 Bs[3][2048];   // 4KB: 64gc x 32k (4 gates x 16m)

  const int tid = threadIdx.x;
  const int w = tid >> 6, l = tid & 63;
  const int lr = l & 15, lh = l >> 4;

  f32x4 acc[4];
  #pragma unroll
  for(int g=0;g<4;g++) acc[g] = (f32x4){0.f,0.f,0.f,0.f};

  // uniform: each wave issues exactly 1 A-DMA + 1 B-DMA (1KB each) per chunk
  auto stage = [&](int kc, int b){
    const u16* aB = (kc < 10) ? (srcX + (size_t)kc*2048) : (srcH + (size_t)(kc-10)*2048);
    const u16* bB = srcW + (size_t)kc*2048;
    g2lds16((const char*)aB + w*1024 + l*16, (char*)&As[b][0] + w*1024);
    g2lds16((const char*)bB + w*1024 + l*16, (char*)&Bs[b][0] + w*1024);
  };

  stage(0, 0);
  stage(1, 1);
  #pragma unroll
  for(int kc=0; kc<26; ++kc){
    // outstanding/wave: chunk kc (2, oldest) + chunk kc+1 (2) -> wait kc done
    if(kc < 25) asm volatile("s_waitcnt vmcnt(2)" ::: "memory");
    else        asm volatile("s_waitcnt vmcnt(0)" ::: "memory");
    __builtin_amdgcn_s_barrier();
    __builtin_amdgcn_sched_barrier(0);
    if(kc+2 < 26) stage(kc+2, (kc+2)%3);     // buffer (kc+2)%3 last read at compute(kc-1), done
    const int cu = kc % 3;
    s16x8 av = *(const s16x8*)&As[cu][(w*16 + lr)*32 + lh*8];
    #pragma unroll
    for(int g=0; g<4; ++g){
      s16x8 bv = *(const s16x8*)&Bs[cu][(g*16 + lr)*32 + lh*8];
      acc[g] = __builtin_amdgcn_mfma_f32_16x16x32_bf16(av, bv, acc[g], 0,0,0);
    }
  }

  // ---- cell update epilogue; c,h in packed tiles ----
  const float* bias = dir ? b_b : b_f;
  const int m = ms*16 + lr;                        // dir-local m in [0,512)
  const float bi = bias[m], bfv = bias[H_+m], bg = bias[2*H_+m], bo = bias[3*H_+m];
  float* cp = cpk + ((size_t)(dir*32+nt)*32 + ms)*1024;            // [64][16] f32
  u16* hop = hpk_out + ((size_t)(dir*32+nt)*16 + (ms>>1))*2048 + (ms&1)*16;
  const int n0 = nt*64;
  #pragma unroll
  for(int r=0; r<4; ++r){
    const int row = w*16 + lh*4 + r;
    float gi = acc[0][r] + bi;
    float gf = acc[1][r] + bfv;
    float gc = acc[2][r] + bg;
    float go = acc[3][r] + bo;
    float c_old = cp[row*16 + lr];
    float c2 = sigm(gf)*c_old + sigm(gi)*tanhf(gc);
    float h2 = sigm(go)*tanhf(c2);
    cp[row*16 + lr] = c2;
    if(t == TW_-1) featsbf[(size_t)(n0+row)*E_ + dir*H_ + m] = f2bf(h2);
    else           hop[row*32 + lr] = f2bf(h2);
  }
}

// ===========================================================================
// q = feats @ W_att  (one-time, bf16 MFMA, fp32 out)  [verified]
// ===========================================================================
__global__ __launch_bounds__(256) void k_qgemm(const u16* __restrict__ featsbf,
                                               const u16* __restrict__ WattT,
                                               float* __restrict__ q)
{
  const int n0 = blockIdx.x*64, j0 = blockIdx.y*64;
  __shared__ __align__(16) u16 As[64*40];
  __shared__ __align__(16) u16 Bs[64*40];
  const int tid = threadIdx.x;
  const int w = tid>>6, l = tid&63, lr = l&15, lk = (l>>4)*8;
  const int arow = tid>>2, ak8 = (tid&3)*8;

  f32x4 acc[4];
  #pragma unroll
  for(int i=0;i<4;i++) acc[i] = (f32x4){0.f,0.f,0.f,0.f};

  for(int kc=0; kc<32; ++kc){
    *(s16x8*)&As[arow*40 + ak8] = *(const s16x8*)&featsbf[(size_t)(n0+arow)*E_ + kc*32 + ak8];
    *(s16x8*)&Bs[arow*40 + ak8] = *(const s16x8*)&WattT[(size_t)(j0+arow)*E_ + kc*32 + ak8];
    __syncthreads();
    s16x8 av = *(const s16x8*)&As[(w*16 + lr)*40 + lk];
    #pragma unroll
    for(int mf=0; mf<4; ++mf){
      s16x8 bv = *(const s16x8*)&Bs[(mf*16 + lr)*40 + lk];
      acc[mf] = __builtin_amdgcn_mfma_f32_16x16x32_bf16(av, bv, acc[mf], 0,0,0);
    }
    __syncthreads();
  }
  #pragma unroll
  for(int mf=0; mf<4; ++mf)
    #pragma unroll
    for(int r=0; r<4; ++r){
      int n = n0 + w*16 + (l>>4)*4 + r;
      q[(size_t)n*E_ + j0 + mf*16 + lr] = acc[mf][r];
    }
}

// ===========================================================================
// Phase 2 building blocks  [bodies unchanged - verified R4-R9]
// ===========================================================================
struct GArg2 {
  const u16* xA; const u16* xB;
  long ldA; long ldB;
  const u16* W; int K;
};

__device__ __forceinline__ void gemm32v2(const GArg2 a, int R, int xt, int ks,
                                         int KS, int z, float* __restrict__ part,
                                         char* smem)
{
  u16* Xs0 = (u16*)smem;
  u16* Xs1 = Xs0 + 32*40;
  u16* Ws0 = Xs1 + 32*40;
  u16* Ws1 = Ws0 + 128*32;
  const int Kc = a.K / KS;
  const int nch = Kc >> 5;
  const int kb0 = ks * Kc;
  const int tid = threadIdx.x;
  const int w = tid>>6, l = tid&63, lr = l&15, lh = l>>4;

  f32x4 a00={0,0,0,0}, a01={0,0,0,0}, a10={0,0,0,0}, a11={0,0,0,0};

  auto issueW = [&](int c, u16* Wb){
    const int kb = kb0 + c*32;
    #pragma unroll
    for(int c2=0;c2<2;++c2){
      const int cc = w*2 + c2;
      const char* g = (const char*)(a.W + (size_t)(xt*128 + cc*16 + (l>>2))*a.K + kb) + (l&3)*16;
      g2lds16(g, (char*)Wb + cc*1024);
    }
  };
  auto loadX = [&](int c, short4* xr){
    const int kb = kb0 + c*32;
    const int row = tid>>3, k4 = (tid&7)*4;
    short4 xv = *(const short4*)&a.xA[(size_t)row*a.ldA + kb + k4];
    if(a.xB){
      short4 yv = *(const short4*)&a.xB[(size_t)row*a.ldB + kb + k4];
      xv.x = (short)f2bf(bf2f((u16)xv.x)+bf2f((u16)yv.x));
      xv.y = (short)f2bf(bf2f((u16)xv.y)+bf2f((u16)yv.y));
      xv.z = (short)f2bf(bf2f((u16)xv.z)+bf2f((u16)yv.z));
      xv.w = (short)f2bf(bf2f((u16)xv.w)+bf2f((u16)yv.w));
    }
    *xr = xv;
  };
  auto writeX = [&](short4 xv, u16* Xb){
    *(short4*)&Xb[(tid>>3)*40 + (tid&7)*4] = xv;
  };

  short4 xr;
  issueW(0, Ws0); loadX(0, &xr); writeX(xr, Xs0);
  __syncthreads();
  for(int c=0;c<nch;++c){
    u16* Xc = (c&1)?Xs1:Xs0; u16* Wc = (c&1)?Ws1:Ws0;
    u16* Xn = (c&1)?Xs0:Xs1; u16* Wn = (c&1)?Ws0:Ws1;
    const bool pre = (c+1 < nch);
    if(pre){ issueW(c+1, Wn); loadX(c+1, &xr); }
    s16x8 av0 = *(const s16x8*)&Xc[lr*40 + lh*8];
    s16x8 av1 = *(const s16x8*)&Xc[(16+lr)*40 + lh*8];
    s16x8 bv0 = *(const s16x8*)&Wc[(w*32 + lr)*32 + lh*8];
    s16x8 bv1 = *(const s16x8*)&Wc[(w*32 + 16 + lr)*32 + lh*8];
    a00 = __builtin_amdgcn_mfma_f32_16x16x32_bf16(av0, bv0, a00, 0,0,0);
    a01 = __builtin_amdgcn_mfma_f32_16x16x32_bf16(av0, bv1, a01, 0,0,0);
    a10 = __builtin_amdgcn_mfma_f32_16x16x32_bf16(av1, bv0, a10, 0,0,0);
    a11 = __builtin_amdgcn_mfma_f32_16x16x32_bf16(av1, bv1, a11, 0,0,0);
    if(pre) writeX(xr, Xn);
    __syncthreads();
  }
  float* dst = part + (size_t)((z*KS + ks)*B_)*R + xt*128 + w*32;
  f32x4 accs[2][2] = {{a00,a01},{a10,a11}};
  #pragma unroll
  for(int nf=0; nf<2; ++nf)
    #pragma unroll
    for(int mf=0; mf<2; ++mf)
      #pragma unroll
      for(int r=0; r<4; ++r){
        int n = nf*16 + lh*4 + r;
        dst[(size_t)n*R + mf*16 + lr] = accs[nf][mf][r];
      }
}

__device__ __forceinline__ void att_body(const float* __restrict__ q,
                                         const u16* __restrict__ histbf,
                                         const u16* __restrict__ featsbf,
                                         u16* __restrict__ xcbf,
                                         int i, int b, char* smem)
{
  float* qs = (float*)smem;      // 1024
  float* sc = qs + E_;           // 64
  const int tid = threadIdx.x;
  *(float4*)&qs[tid*4] = *(const float4*)&q[((size_t)b*T_ + i)*E_ + tid*4];
  __syncthreads();
  const int wv = tid>>6, ln = tid&63;
  for(int L = wv; L <= i; L += 4){
    const u16* hl = histbf + ((size_t)L*B_ + b)*E_;
    float s = 0.f;
    s16x8 h0 = *(const s16x8*)&hl[ln*16];
    s16x8 h1 = *(const s16x8*)&hl[ln*16 + 8];
    #pragma unroll
    for(int j=0;j<8;j++){
      s += qs[ln*16 + j]     * bf2f((u16)h0[j]);
      s += qs[ln*16 + 8 + j] * bf2f((u16)h1[j]);
    }
    #pragma unroll
    for(int off=32; off; off>>=1) s += __shfl_down(s, off);
    if(ln == 0) sc[L] = s;
  }
  __syncthreads();
  if(tid < 64){
    float v  = (tid <= i) ? sc[tid] : -INFINITY;
    float mx = v;
    #pragma unroll
    for(int off=32; off; off>>=1) mx = fmaxf(mx, __shfl_xor(mx, off));
    float ex = (tid <= i) ? expf(v - mx) : 0.f;
    float sm = ex;
    #pragma unroll
    for(int off=32; off; off>>=1) sm += __shfl_xor(sm, off);
    sc[tid] = ex / sm;
  }
  __syncthreads();
  const int e4 = tid*4;
  float c0=0.f, c1=0.f, c2=0.f, c3=0.f;
  for(int L=0; L<=i; ++L){
    float wl = sc[L];
    short4 hv = *(const short4*)&histbf[((size_t)L*B_ + b)*E_ + e4];
    c0 += wl*bf2f((u16)hv.x);
    c1 += wl*bf2f((u16)hv.y);
    c2 += wl*bf2f((u16)hv.z);
    c3 += wl*bf2f((u16)hv.w);
  }
  const u16* xi = featsbf + ((size_t)b*T_ + i)*E_ + e4;
  xcbf[(size_t)b*E_ + e4 + 0] = f2bf(bf2f(xi[0]) + c0);
  xcbf[(size_t)b*E_ + e4 + 1] = f2bf(bf2f(xi[1]) + c1);
  xcbf[(size_t)b*E_ + e4 + 2] = f2bf(bf2f(xi[2]) + c2);
  xcbf[(size_t)b*E_ + e4 + 3] = f2bf(bf2f(xi[3]) + c3);
}

__device__ __forceinline__ void gru_comb(const float* __restrict__ part, int R, int J, int KS,
                                         const float* __restrict__ bih, const float* __restrict__ bhh,
                                         const float* __restrict__ hprev_f,
                                         float* __restrict__ dst_f,
                                         u16* __restrict__ dstbf,
                                         float* __restrict__ dst_seq, int idx)
{
  const int b = idx / J, e = idx - b*J;
  float ir=0.f, iz=0.f, in_=0.f, hr=0.f, hz=0.f, hn=0.f;
  for(int ks=0; ks<KS; ++ks){
    const float* p0 = part + (size_t)(ks*B_ + b)*R;
    const float* p1 = part + (size_t)((KS+ks)*B_ + b)*R;
    ir += p0[e]; iz += p0[J+e]; in_ += p0[2*J+e];
    hr += p1[e]; hz += p1[J+e]; hn  += p1[2*J+e];
  }
  ir += bih[e]; iz += bih[J+e]; in_ += bih[2*J+e];
  hr += bhh[e]; hz += bhh[J+e]; hn  += bhh[2*J+e];
  const float r = sigm(ir + hr);
  const float z = sigm(iz + hz);
  const float n = tanhf(in_ + r*hn);
  const float hp = hprev_f[(size_t)b*J + e];
  const float h2 = (1.f - z)*n + z*hp;
  dst_f[(size_t)b*J + e] = h2;
  dstbf[(size_t)b*J + e] = f2bf(h2);
  if(dst_seq) dst_seq[(size_t)b*J + e] = h2;
}

// M(i): g-gemm(i) [384] | att(i) [32] | p-comb(i-1) [128] | e-comb(i-2) [64]
// grid 608.  No intra-kernel RAW: p-comb writes party[(i-1)&1], g-gemm reads
// party[i&1]; e-comb writes emo (unread here); att reads hist[0..i] (all old).
__global__ __launch_bounds__(256) void k_M(GArg2 g0, GArg2 g1,
    float* __restrict__ part_g,
    const float* __restrict__ q, const u16* __restrict__ histbf,
    const u16* __restrict__ featsbf, u16* __restrict__ xcbf,
    const float* __restrict__ part_p, const float* __restrict__ p_bih,
    const float* __restrict__ p_bhh, float* __restrict__ partyf_pm1,
    u16* __restrict__ partybf_pm1,
    const float* __restrict__ part_e, const float* __restrict__ e_bih,
    const float* __restrict__ e_bhh, float* __restrict__ emof,
    u16* __restrict__ emobf, float* __restrict__ emo_seq, int i)
{
  __shared__ __align__(16) char smem[21504];
  const int x = blockIdx.x;
  if(x < 384){
    if(i >= T_) return;
    const int xt = x % 24, ks = (x/24) & 7, z = x/192;
    gemm32v2(z ? g1 : g0, 3*E_, xt, ks, 8, z, part_g, smem);
  } else if(x < 416){
    if(i >= T_) return;
    att_body(q, histbf, featsbf, xcbf, i, x-384, smem);
  } else if(x < 544){
    const int ip = i-1;
    if(ip < 0 || ip >= T_) return;
    gru_comb(part_p, 3*E_, E_, 8, p_bih, p_bhh, partyf_pm1, partyf_pm1,
             partybf_pm1, nullptr, (x-416)*256 + (int)threadIdx.x);
  } else {
    const int ie = i-2;
    if(ie < 0 || ie >= T_) return;
    gru_comb(part_e, 3*HH_, HH_, 8, e_bih, e_bhh, emof, emof, emobf,
             emo_seq + (size_t)ie*B_*HH_, (x-544)*256 + (int)threadIdx.x);
  }
}

// B2(i): g-comb(i) [128] | p-gemm(i) [384] | e-gemm(i-1) [192]   grid 704
__global__ __launch_bounds__(256) void k_B2(GArg2 p0, GArg2 p1, GArg2 e0, GArg2 e1,
    const float* __restrict__ part_g,
    const float* __restrict__ g_bih, const float* __restrict__ g_bhh,
    const float* __restrict__ gf_prev, float* __restrict__ gf_next,
    u16* __restrict__ histbf,
    float* __restrict__ part_p, float* __restrict__ part_e, int i)
{
  __shared__ __align__(16) char smem[21504];
  const int x = blockIdx.x;
  if(x < 128){
    if(i >= T_) return;
    gru_comb(part_g, 3*E_, E_, 8, g_bih, g_bhh, gf_prev, gf_next,
             histbf + (size_t)(i+1)*B_*E_, nullptr, x*256 + (int)threadIdx.x);
  } else if(x < 512){
    if(i >= T_) return;
    const int ix = x-128, xt = ix % 24, ks = (ix/24) & 7, z = ix/192;
    gemm32v2(z ? p1 : p0, 3*E_, xt, ks, 8, z, part_p, smem);
  } else {
    if(i < 1) return;           // e-gemm(i-1), valid for 1<=i<=64
    const int ix = x-512, xt = ix % 12, ks = (ix/12) & 7, z = ix/96;
    gemm32v2(z ? e1 : e0, 3*HH_, xt, ks, 8, z, part_e, smem);
  }
}

// classifier
__global__ __launch_bounds__(256) void classify(const float* __restrict__ emo_seq,
    const float* __restrict__ clsW, const float* __restrict__ clsb, float* __restrict__ out)
{
  const int idx = blockIdx.x*256 + threadIdx.x;
  if(idx >= B_*T_*C_) return;
  const int c = idx % C_;
  const int bt = idx / C_;
  const int t = bt % T_, b = bt / T_;
  const float* e = emo_seq + (size_t)(t*B_ + b)*HH_;
  const float* w = clsW + (size_t)c*HH_;
  float s = clsb[c];
  for(int h=0; h<HH_; ++h) s += e[h]*w[h];
  out[idx] = s;
}

// ===========================================================================
extern "C" void kernel_launch(void* const* d_in, const int* in_sizes, int n_in,
                              void* d_out, int out_size, void* d_ws, size_t ws_size,
                              hipStream_t stream)
{
  const float* input  = (const float*)d_in[0];
  const float* Wih_f  = (const float*)d_in[1];
  const float* Whh_f  = (const float*)d_in[2];
  const float* b_f    = (const float*)d_in[3];
  const float* Wih_b  = (const float*)d_in[4];
  const float* Whh_b  = (const float*)d_in[5];
  const float* b_b    = (const float*)d_in[6];
  const float* W_att  = (const float*)d_in[7];
  const float* g_Wih  = (const float*)d_in[8];
  const float* g_Whh  = (const float*)d_in[9];
  const float* g_bih  = (const float*)d_in[10];
  const float* g_bhh  = (const float*)d_in[11];
  const float* p_Wih  = (const float*)d_in[12];
  const float* p_Whh  = (const float*)d_in[13];
  const float* p_bih  = (const float*)d_in[14];
  const float* p_bhh  = (const float*)d_in[15];
  const float* e_Wih  = (const float*)d_in[16];
  const float* e_Whh  = (const float*)d_in[17];
  const float* e_bih  = (const float*)d_in[18];
  const float* e_bhh  = (const float*)d_in[19];
  const float* cls_W  = (const float*)d_in[20];
  const float* cls_b  = (const float*)d_in[21];

  // ---- workspace layout ----
  char* base = (char*)d_ws;
  size_t off = 0;
  auto alloc = [&](size_t bytes)->char*{
    char* p = base + off; off += (bytes + 255) & ~(size_t)255; return p;
  };
  u16*   Wpk2    = (u16*)alloc((size_t)64*26*2048*2);       // 6.8 MB
  u16*   xpk     = (u16*)alloc((size_t)32*32*10*2048*2);    // 41.9 MB (phase1 only)
  u16*   hpkA    = (u16*)alloc((size_t)2*32*16*2048*2);     // 4.19 MB (phase1 only)
  u16*   hpkB    = (u16*)alloc((size_t)2*32*16*2048*2);     // 4.19 MB (phase1 only, adjacent)
  float* cpk     = (float*)alloc((size_t)2*32*32*1024*4);   // 8.39 MB (phase1 only)
  u16*   featsbf = (u16*)alloc((size_t)N_*E_*2);
  u16*   eWih    = (u16*)alloc((size_t)3*HH_*E_*2);
  u16*   eWhh    = (u16*)alloc((size_t)3*HH_*HH_*2);
  u16*   histbf  = (u16*)alloc((size_t)(T_+1)*B_*E_*2);
  float* gfbuf   = (float*)alloc((size_t)2*B_*E_*4);
  float* partyf  = (float*)alloc((size_t)2*B_*E_*4);
  u16*   partybf = (u16*)alloc((size_t)2*B_*E_*2);
  float* emof    = (float*)alloc((size_t)B_*HH_*4);
  u16*   emobf   = (u16*)alloc((size_t)B_*HH_*2);
  float* emo_seq = (float*)alloc((size_t)T_*B_*HH_*4);
  u16*   xcbf    = (u16*)alloc((size_t)B_*E_*2);
  float* part_p  = (float*)alloc((size_t)16*B_*3*E_*4);     // 6.29 MB
  // phase-2 buffers aliased into phase-1-only regions:
  u16*   gWih    = (u16*)((char*)xpk + 0);                  // 6.29 MB
  u16*   gWhh    = (u16*)((char*)xpk + 6291456);            // 6.29 MB
  u16*   pWih    = (u16*)((char*)xpk + 12582912);           // 6.29 MB
  u16*   pWhh    = (u16*)((char*)xpk + 18874368);           // 6.29 MB
  float* part_e  = (float*)((char*)xpk + 25165824);         // 3.15 MB
  float* q       = (float*)((char*)xpk + 28311552);         // 8.39 MB
  u16*   WattT   = (u16*)((char*)xpk + 36700160);           // 2.10 MB (ends 38.8 <= 41.9)
  float* part_g  = (float*)hpkA;                            // 6.29 MB (spans hpkA+hpkB, both dead)

  // ---- zero-init ----
  hipMemsetAsync(hpkA,    0, (size_t)2*32*16*2048*2, stream);
  hipMemsetAsync(cpk,     0, (size_t)2*32*32*1024*4, stream);
  hipMemsetAsync(histbf,  0, (size_t)B_*E_*2, stream);        // slice 0
  hipMemsetAsync(gfbuf,   0, (size_t)B_*E_*4, stream);        // slice 0
  hipMemsetAsync(partyf,  0, (size_t)2*B_*E_*4, stream);
  hipMemsetAsync(partybf, 0, (size_t)2*B_*E_*2, stream);
  hipMemsetAsync(emof,    0, (size_t)B_*HH_*4, stream);
  hipMemsetAsync(emobf,   0, (size_t)B_*HH_*2, stream);

  // ---- pre-pass packing (phase 1 inputs) ----
  k_pack_w<<<dim3(((size_t)64*26*2048 + 255)/256), 256, 0, stream>>>(Wih_f, Whh_f, Wih_b, Whh_b, Wpk2);
  k_pack_x<<<dim3(((size_t)32*32*10*2048 + 255)/256), 256, 0, stream>>>(input, xpk);

  // ---- Phase 1: BiLSTM, 2048 blocks (6/CU resident) per step ----
  for(int t=0; t<TW_; ++t){
    u16* hin  = (t & 1) ? hpkB : hpkA;
    u16* hout = (t & 1) ? hpkA : hpkB;
    lstm6<<<dim3(64, 32), 256, 0, stream>>>(xpk, Wpk2, b_f, b_b, hin, hout, cpk, featsbf, t);
  }

  // ---- phase-2 weight conversions (AFTER phase 1: they alias xpk) ----
  k_f2bf<<<dim3((3*E_*E_+255)/256), 256, 0, stream>>>(g_Wih, gWih, 3*E_*E_);
  k_f2bf<<<dim3((3*E_*E_+255)/256), 256, 0, stream>>>(g_Whh, gWhh, 3*E_*E_);
  k_f2bf<<<dim3((3*E_*E_+255)/256), 256, 0, stream>>>(p_Wih, pWih, 3*E_*E_);
  k_f2bf<<<dim3((3*E_*E_+255)/256), 256, 0, stream>>>(p_Whh, pWhh, 3*E_*E_);
  k_f2bf<<<dim3((3*HH_*E_+255)/256), 256, 0, stream>>>(e_Wih, eWih, 3*HH_*E_);
  k_f2bf<<<dim3((3*HH_*HH_+255)/256), 256, 0, stream>>>(e_Whh, eWhh, 3*HH_*HH_);
  k_wattT<<<dim3((E_*E_+255)/256), 256, 0, stream>>>(W_att, WattT);

  // ---- q = feats @ W_att ----
  k_qgemm<<<dim3(32, 16), 256, 0, stream>>>(featsbf, WattT, q);

  // ---- Phase 2: 2 launches/step (M + B2), i = 0..65 ----
  for(int i=0; i<=T_+1; ++i){
    GArg2 ga0{ featsbf + (size_t)i*E_, partybf + (size_t)(i&1)*B_*E_, (long)T_*E_, (long)E_, gWih, E_ };
    GArg2 ga1{ histbf + (size_t)i*B_*E_, nullptr, (long)E_, 0, gWhh, E_ };
    k_M<<<dim3(608), 256, 0, stream>>>(ga0, ga1, part_g, q, histbf, featsbf, xcbf,
                                       part_p, p_bih, p_bhh,
                                       partyf + (size_t)((i-1)&1)*B_*E_,
                                       partybf + (size_t)((i-1)&1)*B_*E_,
                                       part_e, e_bih, e_bhh, emof, emobf, emo_seq, i);
    if(i <= T_){
      GArg2 pa0{ xcbf, nullptr, (long)E_, 0, pWih, E_ };
      GArg2 pa1{ partybf + (size_t)(i&1)*B_*E_, nullptr, (long)E_, 0, pWhh, E_ };
      GArg2 ea0{ partybf + (size_t)((i-1)&1)*B_*E_, nullptr, (long)E_, 0, eWih, E_ };
      GArg2 ea1{ emobf, nullptr, (long)HH_, 0, eWhh, HH_ };
      k_B2<<<dim3(704), 256, 0, stream>>>(pa0, pa1, ea0, ea1, part_g,
                                          g_bih, g_bhh,
                                          gfbuf + (size_t)(i&1)*B_*E_,
                                          gfbuf + (size_t)((i+1)&1)*B_*E_,
                                          histbf, part_p, part_e, i);
    }
  }

  // ---- classifier ----
  classify<<<dim3((B_*T_*C_+255)/256), 256, 0, stream>>>(emo_seq, cls_W, cls_b, (float*)d_out);
}

// Round 11
// 2356.668 us; speedup vs baseline: 1.3604x; 1.0371x over previous
//
#include <hip/hip_runtime.h>
#include <math.h>

#define B_  32
#define T_  64
#define TW_ 32
#define EW_ 300
#define H_  512
#define E_  1024
#define HH_ 512
#define C_  7
#define N_  2048   // B*T

typedef float f32x4 __attribute__((ext_vector_type(4)));
typedef short s16x8 __attribute__((ext_vector_type(8)));
typedef unsigned short u16;
typedef unsigned int u32;

__device__ __forceinline__ float sigm(float x){ return 1.f/(1.f+expf(-x)); }
__device__ __forceinline__ float bf2f(u16 u){
  union{float f; unsigned v;} x; x.v = ((unsigned)u)<<16; return x.f;
}
__device__ __forceinline__ u16 f2bf(float f){
  union{float f; unsigned v;} x; x.f = f;
  unsigned r = x.v + 0x7FFF + ((x.v>>16)&1);
  return (u16)(r>>16);
}
// async 16B global->LDS (dest: wave-uniform base + lane*16)
__device__ __forceinline__ void g2lds16(const void* g, void* l){
  __builtin_amdgcn_global_load_lds((const __attribute__((address_space(1))) u32*)g,
                                   (__attribute__((address_space(3))) u32*)l, 16, 0, 0);
}

// ===========================================================================
// Pre-pass packing kernels (verified R10)
// ===========================================================================
// Wpk2[pan(64)=dir*32+ms][kc(26)][row(64)=g*16+ml][32], R = g*512 + ms*16 + ml
__global__ __launch_bounds__(256) void k_pack_w(
    const float* __restrict__ Wih_f, const float* __restrict__ Whh_f,
    const float* __restrict__ Wih_b, const float* __restrict__ Whh_b,
    u16* __restrict__ Wpk2)
{
  size_t idx = (size_t)blockIdx.x*256 + threadIdx.x;
  if(idx >= (size_t)64*26*2048) return;
  int c   = (int)(idx & 31);
  int row = (int)((idx >> 5) & 63);
  int kc  = (int)((idx >> 11) % 26);
  int pan = (int)(idx / ((size_t)26*2048));
  int dir = pan >> 5, ms = pan & 31;
  int g = row >> 4, ml = row & 15;
  int R = g*512 + ms*16 + ml;
  int k = kc*32 + c;
  const float* Wih = dir ? Wih_b : Wih_f;
  const float* Whh = dir ? Whh_b : Whh_f;
  float v = (k < 320) ? ((k < EW_) ? Wih[(size_t)R*EW_ + k] : 0.f)
                      : Whh[(size_t)R*H_ + (k-320)];
  Wpk2[idx] = f2bf(v);
}

// xpk[wt(32)][nt(32)][kc(10)][row(64)][32]; n = nt*64+row, k = kc*32+c
__global__ __launch_bounds__(256) void k_pack_x(
    const float* __restrict__ input, u16* __restrict__ xpk)
{
  size_t idx = (size_t)blockIdx.x*256 + threadIdx.x;
  if(idx >= (size_t)32*32*10*2048) return;
  int c   = (int)(idx & 31);
  int row = (int)((idx >> 5) & 63);
  int kc  = (int)((idx >> 11) % 10);
  int q2  = (int)((idx >> 11) / 10);      // wt*32+nt
  int nt  = q2 & 31, wt = q2 >> 5;
  int n = nt*64 + row;
  int k = kc*32 + c;
  float v = (k < EW_) ? input[((size_t)n*TW_ + wt)*EW_ + k] : 0.f;
  xpk[idx] = f2bf(v);
}

__global__ __launch_bounds__(256) void k_f2bf(const float* __restrict__ src,
                                              u16* __restrict__ dst, int n)
{
  int idx = blockIdx.x*256 + threadIdx.x;
  if(idx < n) dst[idx] = f2bf(src[idx]);
}

__global__ __launch_bounds__(256) void k_wattT(const float* __restrict__ W,
                                               u16* __restrict__ dst)
{
  int idx = blockIdx.x*256 + threadIdx.x;
  if(idx >= E_*E_) return;
  int j = idx >> 10, k = idx & 1023;
  dst[idx] = f2bf(W[(size_t)k*E_ + j]);   // dst[j][k] = W[k][j]
}

// ===========================================================================
// Phase 1 R11: 64n x 64gc tiles, 2-buffer LDS (16KB -> 8 blocks/CU = 32
// waves/CU), 2 barriers/chunk, depth-1 prefetch, counted vmcnt(2).
// grid (64 panels = dir+2*ms, 32 nt) = 2048 blocks.
// ===========================================================================
__global__ __launch_bounds__(256, 8) void lstm7(
    const u16* __restrict__ xpk, const u16* __restrict__ Wpk2,
    const float* __restrict__ b_f, const float* __restrict__ b_b,
    const u16* __restrict__ hpk_in, u16* __restrict__ hpk_out,
    float* __restrict__ cpk, u16* __restrict__ featsbf, int t)
{
  const int pan = blockIdx.x, nt = blockIdx.y;
  const int dir = pan & 1, ms = pan >> 1;          // ms: 16-col m-slice, 0..31
  const int wt = dir ? (TW_-1-t) : t;
  const u16* srcW = Wpk2 + (size_t)(dir*32+ms)*26*2048;
  const u16* srcX = xpk + (size_t)(wt*32+nt)*10*2048;
  const u16* srcH = hpk_in + (size_t)(dir*32+nt)*16*2048;

  __shared__ __align__(16) u16 As[2][2048];   // 4KB: 64n x 32k
  __shared__ __align__(16) u16 Bs[2][2048];   // 4KB: 64gc x 32k

  const int tid = threadIdx.x;
  const int w = tid >> 6, l = tid & 63;
  const int lr = l & 15, lh = l >> 4;

  f32x4 acc[4];
  #pragma unroll
  for(int g=0;g<4;g++) acc[g] = (f32x4){0.f,0.f,0.f,0.f};

  // uniform: each wave issues exactly 1 A-DMA + 1 B-DMA (1KB each) per chunk
  auto stage = [&](int kc, int b){
    const u16* aB = (kc < 10) ? (srcX + (size_t)kc*2048) : (srcH + (size_t)(kc-10)*2048);
    const u16* bB = srcW + (size_t)kc*2048;
    g2lds16((const char*)aB + w*1024 + l*16, (char*)&As[b][0] + w*1024);
    g2lds16((const char*)bB + w*1024 + l*16, (char*)&Bs[b][0] + w*1024);
  };

  stage(0, 0);
  #pragma unroll
  for(int kc=0; kc<26; ++kc){
    // stage(kc+1) into buf[(kc+1)&1]: freed by trailing barrier of iter kc-1
    if(kc+1 < 26) stage(kc+1, (kc+1)&1);
    // outstanding/wave: chunk kc (2, oldest) + chunk kc+1 (2) -> wait kc done
    if(kc < 25) asm volatile("s_waitcnt vmcnt(2)" ::: "memory");
    else        asm volatile("s_waitcnt vmcnt(0)" ::: "memory");
    __builtin_amdgcn_s_barrier();
    __builtin_amdgcn_sched_barrier(0);
    const int cu = kc & 1;
    s16x8 av = *(const s16x8*)&As[cu][(w*16 + lr)*32 + lh*8];
    #pragma unroll
    for(int g=0; g<4; ++g){
      s16x8 bv = *(const s16x8*)&Bs[cu][(g*16 + lr)*32 + lh*8];
      acc[g] = __builtin_amdgcn_mfma_f32_16x16x32_bf16(av, bv, acc[g], 0,0,0);
    }
    if(kc < 25) __builtin_amdgcn_s_barrier();   // free buf[kc&1] for stage(kc+2)
  }

  // ---- cell update epilogue; c,h in packed tiles ----
  const float* bias = dir ? b_b : b_f;
  const int m = ms*16 + lr;                        // dir-local m in [0,512)
  const float bi = bias[m], bfv = bias[H_+m], bg = bias[2*H_+m], bo = bias[3*H_+m];
  float* cp = cpk + ((size_t)(dir*32+nt)*32 + ms)*1024;            // [64][16] f32
  u16* hop = hpk_out + ((size_t)(dir*32+nt)*16 + (ms>>1))*2048 + (ms&1)*16;
  const int n0 = nt*64;
  #pragma unroll
  for(int r=0; r<4; ++r){
    const int row = w*16 + lh*4 + r;
    float gi = acc[0][r] + bi;
    float gf = acc[1][r] + bfv;
    float gc = acc[2][r] + bg;
    float go = acc[3][r] + bo;
    float c_old = cp[row*16 + lr];
    float c2 = sigm(gf)*c_old + sigm(gi)*tanhf(gc);
    float h2 = sigm(go)*tanhf(c2);
    cp[row*16 + lr] = c2;
    if(t == TW_-1) featsbf[(size_t)(n0+row)*E_ + dir*H_ + m] = f2bf(h2);
    else           hop[row*32 + lr] = f2bf(h2);
  }
}

// ===========================================================================
// q = feats @ W_att  (one-time, bf16 MFMA, fp32 out)  [verified]
// ===========================================================================
__global__ __launch_bounds__(256) void k_qgemm(const u16* __restrict__ featsbf,
                                               const u16* __restrict__ WattT,
                                               float* __restrict__ q)
{
  const int n0 = blockIdx.x*64, j0 = blockIdx.y*64;
  __shared__ __align__(16) u16 As[64*40];
  __shared__ __align__(16) u16 Bs[64*40];
  const int tid = threadIdx.x;
  const int w = tid>>6, l = tid&63, lr = l&15, lk = (l>>4)*8;
  const int arow = tid>>2, ak8 = (tid&3)*8;

  f32x4 acc[4];
  #pragma unroll
  for(int i=0;i<4;i++) acc[i] = (f32x4){0.f,0.f,0.f,0.f};

  for(int kc=0; kc<32; ++kc){
    *(s16x8*)&As[arow*40 + ak8] = *(const s16x8*)&featsbf[(size_t)(n0+arow)*E_ + kc*32 + ak8];
    *(s16x8*)&Bs[arow*40 + ak8] = *(const s16x8*)&WattT[(size_t)(j0+arow)*E_ + kc*32 + ak8];
    __syncthreads();
    s16x8 av = *(const s16x8*)&As[(w*16 + lr)*40 + lk];
    #pragma unroll
    for(int mf=0; mf<4; ++mf){
      s16x8 bv = *(const s16x8*)&Bs[(mf*16 + lr)*40 + lk];
      acc[mf] = __builtin_amdgcn_mfma_f32_16x16x32_bf16(av, bv, acc[mf], 0,0,0);
    }
    __syncthreads();
  }
  #pragma unroll
  for(int mf=0; mf<4; ++mf)
    #pragma unroll
    for(int r=0; r<4; ++r){
      int n = n0 + w*16 + (l>>4)*4 + r;
      q[(size_t)n*E_ + j0 + mf*16 + lr] = acc[mf][r];
    }
}

// ===========================================================================
// Phase 2 building blocks.  R11: gemm32v3<NCH> — all chunks staged upfront,
// ONE barrier, then all MFMAs back-to-back. NCH compile-time (2 or 4).
// LDS: Xs[NCH<=4][32*40] (10.0KB) + Ws[NCH<=4][128*32] (32KB) = 43008 B.
// ===========================================================================
struct GArg2 {
  const u16* xA; const u16* xB;
  long ldA; long ldB;
  const u16* W; int K;
};

template<int NCH>
__device__ __forceinline__ void gemm32v3(const GArg2 a, int R, int xt, int ks,
                                         int KS, int z, float* __restrict__ part,
                                         char* smem)
{
  u16* Xs = (u16*)smem;                  // NCH x [32*40]
  u16* Ws = (u16*)smem + 4*1280;         // NCH x [128*32]
  const int Kc = a.K / KS;               // = NCH*32
  const int kb0 = ks * Kc;
  const int tid = threadIdx.x;
  const int w = tid>>6, l = tid&63, lr = l&15, lh = l>>4;

  // issue all W DMAs (2/wave/chunk)
  #pragma unroll
  for(int c=0;c<NCH;++c){
    const int kb = kb0 + c*32;
    #pragma unroll
    for(int c2=0;c2<2;++c2){
      const int cc = w*2 + c2;
      const char* g = (const char*)(a.W + (size_t)(xt*128 + cc*16 + (l>>2))*a.K + kb) + (l&3)*16;
      g2lds16(g, (char*)(Ws + c*4096) + cc*1024);
    }
  }
  // load all X chunks to regs, then write to LDS (compiler inserts waits)
  const int row = tid>>3, k4 = (tid&7)*4;
  short4 xr[NCH];
  #pragma unroll
  for(int c=0;c<NCH;++c){
    const int kb = kb0 + c*32;
    short4 xv = *(const short4*)&a.xA[(size_t)row*a.ldA + kb + k4];
    if(a.xB){
      short4 yv = *(const short4*)&a.xB[(size_t)row*a.ldB + kb + k4];
      xv.x = (short)f2bf(bf2f((u16)xv.x)+bf2f((u16)yv.x));
      xv.y = (short)f2bf(bf2f((u16)xv.y)+bf2f((u16)yv.y));
      xv.z = (short)f2bf(bf2f((u16)xv.z)+bf2f((u16)yv.z));
      xv.w = (short)f2bf(bf2f((u16)xv.w)+bf2f((u16)yv.w));
    }
    xr[c] = xv;
  }
  #pragma unroll
  for(int c=0;c<NCH;++c)
    *(short4*)&Xs[c*1280 + row*40 + k4] = xr[c];

  asm volatile("s_waitcnt vmcnt(0) lgkmcnt(0)" ::: "memory");
  __builtin_amdgcn_s_barrier();
  __builtin_amdgcn_sched_barrier(0);

  f32x4 a00={0,0,0,0}, a01={0,0,0,0}, a10={0,0,0,0}, a11={0,0,0,0};
  #pragma unroll
  for(int c=0;c<NCH;++c){
    const u16* Xc = Xs + c*1280;
    const u16* Wc = Ws + c*4096;
    s16x8 av0 = *(const s16x8*)&Xc[lr*40 + lh*8];
    s16x8 av1 = *(const s16x8*)&Xc[(16+lr)*40 + lh*8];
    s16x8 bv0 = *(const s16x8*)&Wc[(w*32 + lr)*32 + lh*8];
    s16x8 bv1 = *(const s16x8*)&Wc[(w*32 + 16 + lr)*32 + lh*8];
    a00 = __builtin_amdgcn_mfma_f32_16x16x32_bf16(av0, bv0, a00, 0,0,0);
    a01 = __builtin_amdgcn_mfma_f32_16x16x32_bf16(av0, bv1, a01, 0,0,0);
    a10 = __builtin_amdgcn_mfma_f32_16x16x32_bf16(av1, bv0, a10, 0,0,0);
    a11 = __builtin_amdgcn_mfma_f32_16x16x32_bf16(av1, bv1, a11, 0,0,0);
  }
  float* dst = part + (size_t)((z*KS + ks)*B_)*R + xt*128 + w*32;
  f32x4 accs[2][2] = {{a00,a01},{a10,a11}};
  #pragma unroll
  for(int nf=0; nf<2; ++nf)
    #pragma unroll
    for(int mf=0; mf<2; ++mf)
      #pragma unroll
      for(int r=0; r<4; ++r){
        int n = nf*16 + lh*4 + r;
        dst[(size_t)n*R + mf*16 + lr] = accs[nf][mf][r];
      }
}

__device__ __forceinline__ void att_body(const float* __restrict__ q,
                                         const u16* __restrict__ histbf,
                                         const u16* __restrict__ featsbf,
                                         u16* __restrict__ xcbf,
                                         int i, int b, char* smem)
{
  float* qs = (float*)smem;      // 1024
  float* sc = qs + E_;           // 64
  const int tid = threadIdx.x;
  *(float4*)&qs[tid*4] = *(const float4*)&q[((size_t)b*T_ + i)*E_ + tid*4];
  __syncthreads();
  const int wv = tid>>6, ln = tid&63;
  for(int L = wv; L <= i; L += 4){
    const u16* hl = histbf + ((size_t)L*B_ + b)*E_;
    float s = 0.f;
    s16x8 h0 = *(const s16x8*)&hl[ln*16];
    s16x8 h1 = *(const s16x8*)&hl[ln*16 + 8];
    #pragma unroll
    for(int j=0;j<8;j++){
      s += qs[ln*16 + j]     * bf2f((u16)h0[j]);
      s += qs[ln*16 + 8 + j] * bf2f((u16)h1[j]);
    }
    #pragma unroll
    for(int off=32; off; off>>=1) s += __shfl_down(s, off);
    if(ln == 0) sc[L] = s;
  }
  __syncthreads();
  if(tid < 64){
    float v  = (tid <= i) ? sc[tid] : -INFINITY;
    float mx = v;
    #pragma unroll
    for(int off=32; off; off>>=1) mx = fmaxf(mx, __shfl_xor(mx, off));
    float ex = (tid <= i) ? expf(v - mx) : 0.f;
    float sm = ex;
    #pragma unroll
    for(int off=32; off; off>>=1) sm += __shfl_xor(sm, off);
    sc[tid] = ex / sm;
  }
  __syncthreads();
  const int e4 = tid*4;
  float c0=0.f, c1=0.f, c2=0.f, c3=0.f;
  for(int L=0; L<=i; ++L){
    float wl = sc[L];
    short4 hv = *(const short4*)&histbf[((size_t)L*B_ + b)*E_ + e4];
    c0 += wl*bf2f((u16)hv.x);
    c1 += wl*bf2f((u16)hv.y);
    c2 += wl*bf2f((u16)hv.z);
    c3 += wl*bf2f((u16)hv.w);
  }
  const u16* xi = featsbf + ((size_t)b*T_ + i)*E_ + e4;
  xcbf[(size_t)b*E_ + e4 + 0] = f2bf(bf2f(xi[0]) + c0);
  xcbf[(size_t)b*E_ + e4 + 1] = f2bf(bf2f(xi[1]) + c1);
  xcbf[(size_t)b*E_ + e4 + 2] = f2bf(bf2f(xi[2]) + c2);
  xcbf[(size_t)b*E_ + e4 + 3] = f2bf(bf2f(xi[3]) + c3);
}

__device__ __forceinline__ void gru_comb(const float* __restrict__ part, int R, int J, int KS,
                                         const float* __restrict__ bih, const float* __restrict__ bhh,
                                         const float* __restrict__ hprev_f,
                                         float* __restrict__ dst_f,
                                         u16* __restrict__ dstbf,
                                         float* __restrict__ dst_seq, int idx)
{
  const int b = idx / J, e = idx - b*J;
  float ir=0.f, iz=0.f, in_=0.f, hr=0.f, hz=0.f, hn=0.f;
  for(int ks=0; ks<KS; ++ks){
    const float* p0 = part + (size_t)(ks*B_ + b)*R;
    const float* p1 = part + (size_t)((KS+ks)*B_ + b)*R;
    ir += p0[e]; iz += p0[J+e]; in_ += p0[2*J+e];
    hr += p1[e]; hz += p1[J+e]; hn  += p1[2*J+e];
  }
  ir += bih[e]; iz += bih[J+e]; in_ += bih[2*J+e];
  hr += bhh[e]; hz += bhh[J+e]; hn  += bhh[2*J+e];
  const float r = sigm(ir + hr);
  const float z = sigm(iz + hz);
  const float n = tanhf(in_ + r*hn);
  const float hp = hprev_f[(size_t)b*J + e];
  const float h2 = (1.f - z)*n + z*hp;
  dst_f[(size_t)b*J + e] = h2;
  dstbf[(size_t)b*J + e] = f2bf(h2);
  if(dst_seq) dst_seq[(size_t)b*J + e] = h2;
}

// M(i): g-gemm(i) [384] | att(i) [32] | p-comb(i-1) [128] | e-comb(i-2) [64]
// grid 608.  (schedule verified R10)
__global__ __launch_bounds__(256) void k_M(GArg2 g0, GArg2 g1,
    float* __restrict__ part_g,
    const float* __restrict__ q, const u16* __restrict__ histbf,
    const u16* __restrict__ featsbf, u16* __restrict__ xcbf,
    const float* __restrict__ part_p, const float* __restrict__ p_bih,
    const float* __restrict__ p_bhh, float* __restrict__ partyf_pm1,
    u16* __restrict__ partybf_pm1,
    const float* __restrict__ part_e, const float* __restrict__ e_bih,
    const float* __restrict__ e_bhh, float* __restrict__ emof,
    u16* __restrict__ emobf, float* __restrict__ emo_seq, int i)
{
  __shared__ __align__(16) char smem[43008];
  const int x = blockIdx.x;
  if(x < 384){
    if(i >= T_) return;
    const int xt = x % 24, ks = (x/24) & 7, z = x/192;
    gemm32v3<4>(z ? g1 : g0, 3*E_, xt, ks, 8, z, part_g, smem);
  } else if(x < 416){
    if(i >= T_) return;
    att_body(q, histbf, featsbf, xcbf, i, x-384, smem);
  } else if(x < 544){
    const int ip = i-1;
    if(ip < 0 || ip >= T_) return;
    gru_comb(part_p, 3*E_, E_, 8, p_bih, p_bhh, partyf_pm1, partyf_pm1,
             partybf_pm1, nullptr, (x-416)*256 + (int)threadIdx.x);
  } else {
    const int ie = i-2;
    if(ie < 0 || ie >= T_) return;
    gru_comb(part_e, 3*HH_, HH_, 8, e_bih, e_bhh, emof, emof, emobf,
             emo_seq + (size_t)ie*B_*HH_, (x-544)*256 + (int)threadIdx.x);
  }
}

// B2(i): g-comb(i) [128] | p-gemm(i) [384] | e-gemm(i-1) [192]   grid 704
__global__ __launch_bounds__(256) void k_B2(GArg2 p0, GArg2 p1, GArg2 e0, GArg2 e1,
    const float* __restrict__ part_g,
    const float* __restrict__ g_bih, const float* __restrict__ g_bhh,
    const float* __restrict__ gf_prev, float* __restrict__ gf_next,
    u16* __restrict__ histbf,
    float* __restrict__ part_p, float* __restrict__ part_e, int i)
{
  __shared__ __align__(16) char smem[43008];
  const int x = blockIdx.x;
  if(x < 128){
    if(i >= T_) return;
    gru_comb(part_g, 3*E_, E_, 8, g_bih, g_bhh, gf_prev, gf_next,
             histbf + (size_t)(i+1)*B_*E_, nullptr, x*256 + (int)threadIdx.x);
  } else if(x < 512){
    if(i >= T_) return;
    const int ix = x-128, xt = ix % 24, ks = (ix/24) & 7, z = ix/192;
    gemm32v3<4>(z ? p1 : p0, 3*E_, xt, ks, 8, z, part_p, smem);
  } else {
    if(i < 1) return;           // e-gemm(i-1), valid for 1<=i<=64
    const int ix = x-512, xt = ix % 12, ks = (ix/12) & 7, z = ix/96;
    if(z) gemm32v3<2>(e1, 3*HH_, xt, ks, 8, 1, part_e, smem);   // K=512
    else  gemm32v3<4>(e0, 3*HH_, xt, ks, 8, 0, part_e, smem);   // K=1024
  }
}

// classifier
__global__ __launch_bounds__(256) void classify(const float* __restrict__ emo_seq,
    const float* __restrict__ clsW, const float* __restrict__ clsb, float* __restrict__ out)
{
  const int idx = blockIdx.x*256 + threadIdx.x;
  if(idx >= B_*T_*C_) return;
  const int c = idx % C_;
  const int bt = idx / C_;
  const int t = bt % T_, b = bt / T_;
  const float* e = emo_seq + (size_t)(t*B_ + b)*HH_;
  const float* w = clsW + (size_t)c*HH_;
  float s = clsb[c];
  for(int h=0; h<HH_; ++h) s += e[h]*w[h];
  out[idx] = s;
}

// ===========================================================================
extern "C" void kernel_launch(void* const* d_in, const int* in_sizes, int n_in,
                              void* d_out, int out_size, void* d_ws, size_t ws_size,
                              hipStream_t stream)
{
  const float* input  = (const float*)d_in[0];
  const float* Wih_f  = (const float*)d_in[1];
  const float* Whh_f  = (const float*)d_in[2];
  const float* b_f    = (const float*)d_in[3];
  const float* Wih_b  = (const float*)d_in[4];
  const float* Whh_b  = (const float*)d_in[5];
  const float* b_b    = (const float*)d_in[6];
  const float* W_att  = (const float*)d_in[7];
  const float* g_Wih  = (const float*)d_in[8];
  const float* g_Whh  = (const float*)d_in[9];
  const float* g_bih  = (const float*)d_in[10];
  const float* g_bhh  = (const float*)d_in[11];
  const float* p_Wih  = (const float*)d_in[12];
  const float* p_Whh  = (const float*)d_in[13];
  const float* p_bih  = (const float*)d_in[14];
  const float* p_bhh  = (const float*)d_in[15];
  const float* e_Wih  = (const float*)d_in[16];
  const float* e_Whh  = (const float*)d_in[17];
  const float* e_bih  = (const float*)d_in[18];
  const float* e_bhh  = (const float*)d_in[19];
  const float* cls_W  = (const float*)d_in[20];
  const float* cls_b  = (const float*)d_in[21];

  // ---- workspace layout ----
  char* base = (char*)d_ws;
  size_t off = 0;
  auto alloc = [&](size_t bytes)->char*{
    char* p = base + off; off += (bytes + 255) & ~(size_t)255; return p;
  };
  u16*   Wpk2    = (u16*)alloc((size_t)64*26*2048*2);       // 6.8 MB
  u16*   xpk     = (u16*)alloc((size_t)32*32*10*2048*2);    // 41.9 MB (phase1 only)
  u16*   hpkA    = (u16*)alloc((size_t)2*32*16*2048*2);     // 4.19 MB (phase1 only)
  u16*   hpkB    = (u16*)alloc((size_t)2*32*16*2048*2);     // 4.19 MB (phase1 only, adjacent)
  float* cpk     = (float*)alloc((size_t)2*32*32*1024*4);   // 8.39 MB (phase1 only)
  u16*   featsbf = (u16*)alloc((size_t)N_*E_*2);
  u16*   eWih    = (u16*)alloc((size_t)3*HH_*E_*2);
  u16*   eWhh    = (u16*)alloc((size_t)3*HH_*HH_*2);
  u16*   histbf  = (u16*)alloc((size_t)(T_+1)*B_*E_*2);
  float* gfbuf   = (float*)alloc((size_t)2*B_*E_*4);
  float* partyf  = (float*)alloc((size_t)2*B_*E_*4);
  u16*   partybf = (u16*)alloc((size_t)2*B_*E_*2);
  float* emof    = (float*)alloc((size_t)B_*HH_*4);
  u16*   emobf   = (u16*)alloc((size_t)B_*HH_*2);
  float* emo_seq = (float*)alloc((size_t)T_*B_*HH_*4);
  u16*   xcbf    = (u16*)alloc((size_t)B_*E_*2);
  float* part_p  = (float*)alloc((size_t)16*B_*3*E_*4);     // 6.29 MB
  // phase-2 buffers aliased into phase-1-only regions:
  u16*   gWih    = (u16*)((char*)xpk + 0);                  // 6.29 MB
  u16*   gWhh    = (u16*)((char*)xpk + 6291456);            // 6.29 MB
  u16*   pWih    = (u16*)((char*)xpk + 12582912);           // 6.29 MB
  u16*   pWhh    = (u16*)((char*)xpk + 18874368);           // 6.29 MB
  float* part_e  = (float*)((char*)xpk + 25165824);         // 3.15 MB
  float* q       = (float*)((char*)xpk + 28311552);         // 8.39 MB
  u16*   WattT   = (u16*)((char*)xpk + 36700160);           // 2.10 MB (ends 38.8 <= 41.9)
  float* part_g  = (float*)hpkA;                            // 6.29 MB (spans hpkA+hpkB, both dead)

  // ---- zero-init ----
  hipMemsetAsync(hpkA,    0, (size_t)2*32*16*2048*2, stream);
  hipMemsetAsync(cpk,     0, (size_t)2*32*32*1024*4, stream);
  hipMemsetAsync(histbf,  0, (size_t)B_*E_*2, stream);        // slice 0
  hipMemsetAsync(gfbuf,   0, (size_t)B_*E_*4, stream);        // slice 0
  hipMemsetAsync(partyf,  0, (size_t)2*B_*E_*4, stream);
  hipMemsetAsync(partybf, 0, (size_t)2*B_*E_*2, stream);
  hipMemsetAsync(emof,    0, (size_t)B_*HH_*4, stream);
  hipMemsetAsync(emobf,   0, (size_t)B_*HH_*2, stream);

  // ---- pre-pass packing (phase 1 inputs) ----
  k_pack_w<<<dim3(((size_t)64*26*2048 + 255)/256), 256, 0, stream>>>(Wih_f, Whh_f, Wih_b, Whh_b, Wpk2);
  k_pack_x<<<dim3(((size_t)32*32*10*2048 + 255)/256), 256, 0, stream>>>(input, xpk);

  // ---- Phase 1: BiLSTM, 2048 blocks (8/CU resident) per step ----
  for(int t=0; t<TW_; ++t){
    u16* hin  = (t & 1) ? hpkB : hpkA;
    u16* hout = (t & 1) ? hpkA : hpkB;
    lstm7<<<dim3(64, 32), 256, 0, stream>>>(xpk, Wpk2, b_f, b_b, hin, hout, cpk, featsbf, t);
  }

  // ---- phase-2 weight conversions (AFTER phase 1: they alias xpk) ----
  k_f2bf<<<dim3((3*E_*E_+255)/256), 256, 0, stream>>>(g_Wih, gWih, 3*E_*E_);
  k_f2bf<<<dim3((3*E_*E_+255)/256), 256, 0, stream>>>(g_Whh, gWhh, 3*E_*E_);
  k_f2bf<<<dim3((3*E_*E_+255)/256), 256, 0, stream>>>(p_Wih, pWih, 3*E_*E_);
  k_f2bf<<<dim3((3*E_*E_+255)/256), 256, 0, stream>>>(p_Whh, pWhh, 3*E_*E_);
  k_f2bf<<<dim3((3*HH_*E_+255)/256), 256, 0, stream>>>(e_Wih, eWih, 3*HH_*E_);
  k_f2bf<<<dim3((3*HH_*HH_+255)/256), 256, 0, stream>>>(e_Whh, eWhh, 3*HH_*HH_);
  k_wattT<<<dim3((E_*E_+255)/256), 256, 0, stream>>>(W_att, WattT);

  // ---- q = feats @ W_att ----
  k_qgemm<<<dim3(32, 16), 256, 0, stream>>>(featsbf, WattT, q);

  // ---- Phase 2: 2 launches/step (M + B2), i = 0..65 ----
  for(int i=0; i<=T_+1; ++i){
    GArg2 ga0{ featsbf + (size_t)i*E_, partybf + (size_t)(i&1)*B_*E_, (long)T_*E_, (long)E_, gWih, E_ };
    GArg2 ga1{ histbf + (size_t)i*B_*E_, nullptr, (long)E_, 0, gWhh, E_ };
    k_M<<<dim3(608), 256, 0, stream>>>(ga0, ga1, part_g, q, histbf, featsbf, xcbf,
                                       part_p, p_bih, p_bhh,
                                       partyf + (size_t)((i-1)&1)*B_*E_,
                                       partybf + (size_t)((i-1)&1)*B_*E_,
                                       part_e, e_bih, e_bhh, emof, emobf, emo_seq, i);
    if(i <= T_){
      GArg2 pa0{ xcbf, nullptr, (long)E_, 0, pWih, E_ };
      GArg2 pa1{ partybf + (size_t)(i&1)*B_*E_, nullptr, (long)E_, 0, pWhh, E_ };
      GArg2 ea0{ partybf + (size_t)((i-1)&1)*B_*E_, nullptr, (long)E_, 0, eWih, E_ };
      GArg2 ea1{ emobf, nullptr, (long)HH_, 0, eWhh, HH_ };
      k_B2<<<dim3(704), 256, 0, stream>>>(pa0, pa1, ea0, ea1, part_g,
                                          g_bih, g_bhh,
                                          gfbuf + (size_t)(i&1)*B_*E_,
                                          gfbuf + (size_t)((i+1)&1)*B_*E_,
                                          histbf, part_p, part_e, i);
    }
  }

  // ---- classifier ----
  classify<<<dim3((B_*T_*C_+255)/256), 256, 0, stream>>>(emo_seq, cls_W, cls_b, (float*)d_out);
}

// Round 12
// 2337.140 us; speedup vs baseline: 1.3718x; 1.0084x over previous
//
#include <hip/hip_runtime.h>
#include <math.h>

#define B_  32
#define T_  64
#define TW_ 32
#define EW_ 300
#define H_  512
#define E_  1024
#define HH_ 512
#define C_  7
#define N_  2048   // B*T

typedef float f32x4 __attribute__((ext_vector_type(4)));
typedef short s16x8 __attribute__((ext_vector_type(8)));
typedef unsigned short u16;
typedef unsigned int u32;

__device__ __forceinline__ float sigm(float x){ return 1.f/(1.f+expf(-x)); }
__device__ __forceinline__ float bf2f(u16 u){
  union{float f; unsigned v;} x; x.v = ((unsigned)u)<<16; return x.f;
}
__device__ __forceinline__ u16 f2bf(float f){
  union{float f; unsigned v;} x; x.f = f;
  unsigned r = x.v + 0x7FFF + ((x.v>>16)&1);
  return (u16)(r>>16);
}
// async 16B global->LDS (dest: wave-uniform base + lane*16)
__device__ __forceinline__ void g2lds16(const void* g, void* l){
  __builtin_amdgcn_global_load_lds((const __attribute__((address_space(1))) u32*)g,
                                   (__attribute__((address_space(3))) u32*)l, 16, 0, 0);
}

// ===========================================================================
// Pre-pass packing kernels (verified R10/R11)
// ===========================================================================
// Wpk2[pan(64)=dir*32+ms][kc(26)][row(64)=g*16+ml][32], R = g*512 + ms*16 + ml
__global__ __launch_bounds__(256) void k_pack_w(
    const float* __restrict__ Wih_f, const float* __restrict__ Whh_f,
    const float* __restrict__ Wih_b, const float* __restrict__ Whh_b,
    u16* __restrict__ Wpk2)
{
  size_t idx = (size_t)blockIdx.x*256 + threadIdx.x;
  if(idx >= (size_t)64*26*2048) return;
  int c   = (int)(idx & 31);
  int row = (int)((idx >> 5) & 63);
  int kc  = (int)((idx >> 11) % 26);
  int pan = (int)(idx / ((size_t)26*2048));
  int dir = pan >> 5, ms = pan & 31;
  int g = row >> 4, ml = row & 15;
  int R = g*512 + ms*16 + ml;
  int k = kc*32 + c;
  const float* Wih = dir ? Wih_b : Wih_f;
  const float* Whh = dir ? Whh_b : Whh_f;
  float v = (k < 320) ? ((k < EW_) ? Wih[(size_t)R*EW_ + k] : 0.f)
                      : Whh[(size_t)R*H_ + (k-320)];
  Wpk2[idx] = f2bf(v);
}

// xpk[wt(32)][nt(32)][kc(10)][row(64)][32]; n = nt*64+row, k = kc*32+c
__global__ __launch_bounds__(256) void k_pack_x(
    const float* __restrict__ input, u16* __restrict__ xpk)
{
  size_t idx = (size_t)blockIdx.x*256 + threadIdx.x;
  if(idx >= (size_t)32*32*10*2048) return;
  int c   = (int)(idx & 31);
  int row = (int)((idx >> 5) & 63);
  int kc  = (int)((idx >> 11) % 10);
  int q2  = (int)((idx >> 11) / 10);      // wt*32+nt
  int nt  = q2 & 31, wt = q2 >> 5;
  int n = nt*64 + row;
  int k = kc*32 + c;
  float v = (k < EW_) ? input[((size_t)n*TW_ + wt)*EW_ + k] : 0.f;
  xpk[idx] = f2bf(v);
}

// ONE fused conversion kernel for all phase-2 weights (replaces 7 launches)
__global__ __launch_bounds__(256) void k_prep2(
    const float* __restrict__ g_Wih, const float* __restrict__ g_Whh,
    const float* __restrict__ p_Wih, const float* __restrict__ p_Whh,
    const float* __restrict__ e_Wih, const float* __restrict__ e_Whh,
    const float* __restrict__ W_att,
    u16* __restrict__ gWih, u16* __restrict__ gWhh,
    u16* __restrict__ pWih, u16* __restrict__ pWhh,
    u16* __restrict__ eWih, u16* __restrict__ eWhh,
    u16* __restrict__ WattT)
{
  int idx = blockIdx.x*256 + threadIdx.x;
  if(idx < 3145728){ gWih[idx] = f2bf(g_Wih[idx]); return; }
  idx -= 3145728;
  if(idx < 3145728){ gWhh[idx] = f2bf(g_Whh[idx]); return; }
  idx -= 3145728;
  if(idx < 3145728){ pWih[idx] = f2bf(p_Wih[idx]); return; }
  idx -= 3145728;
  if(idx < 3145728){ pWhh[idx] = f2bf(p_Whh[idx]); return; }
  idx -= 3145728;
  if(idx < 1572864){ eWih[idx] = f2bf(e_Wih[idx]); return; }
  idx -= 1572864;
  if(idx < 786432){ eWhh[idx] = f2bf(e_Whh[idx]); return; }
  idx -= 786432;
  if(idx < 1048576){
    int j = idx >> 10, k = idx & 1023;
    WattT[idx] = f2bf(W_att[(size_t)k*E_ + j]);   // WattT[j][k] = W[k][j]
  }
}

// ONE fused zero-init kernel for small recurrent state (replaces 6 memsets)
__global__ __launch_bounds__(256) void k_init0(
    u16* __restrict__ histbf, float* __restrict__ gfbuf,
    float* __restrict__ partyf, u16* __restrict__ partybf,
    float* __restrict__ emof, u16* __restrict__ emobf)
{
  const int idx = blockIdx.x*256 + threadIdx.x;
  if(idx < B_*E_){ histbf[idx] = 0; gfbuf[idx] = 0.f; }
  if(idx < 2*B_*E_){ partyf[idx] = 0.f; partybf[idx] = 0; }
  if(idx < B_*HH_){ emof[idx] = 0.f; emobf[idx] = 0; }
}

// ===========================================================================
// Phase 1 (verified R11): 64n x 64gc tiles, 2-buffer LDS (16KB -> 8
// blocks/CU = 32 waves/CU = occupancy ceiling), 2 barriers/chunk, depth-1
// prefetch, counted vmcnt(2). grid (64 panels, 32 nt) = 2048 blocks.
// ===========================================================================
__global__ __launch_bounds__(256, 8) void lstm7(
    const u16* __restrict__ xpk, const u16* __restrict__ Wpk2,
    const float* __restrict__ b_f, const float* __restrict__ b_b,
    const u16* __restrict__ hpk_in, u16* __restrict__ hpk_out,
    float* __restrict__ cpk, u16* __restrict__ featsbf, int t)
{
  const int pan = blockIdx.x, nt = blockIdx.y;
  const int dir = pan & 1, ms = pan >> 1;          // ms: 16-col m-slice, 0..31
  const int wt = dir ? (TW_-1-t) : t;
  const u16* srcW = Wpk2 + (size_t)(dir*32+ms)*26*2048;
  const u16* srcX = xpk + (size_t)(wt*32+nt)*10*2048;
  const u16* srcH = hpk_in + (size_t)(dir*32+nt)*16*2048;

  __shared__ __align__(16) u16 As[2][2048];   // 4KB: 64n x 32k
  __shared__ __align__(16) u16 Bs[2][2048];   // 4KB: 64gc x 32k

  const int tid = threadIdx.x;
  const int w = tid >> 6, l = tid & 63;
  const int lr = l & 15, lh = l >> 4;

  f32x4 acc[4];
  #pragma unroll
  for(int g=0;g<4;g++) acc[g] = (f32x4){0.f,0.f,0.f,0.f};

  auto stage = [&](int kc, int b){
    const u16* aB = (kc < 10) ? (srcX + (size_t)kc*2048) : (srcH + (size_t)(kc-10)*2048);
    const u16* bB = srcW + (size_t)kc*2048;
    g2lds16((const char*)aB + w*1024 + l*16, (char*)&As[b][0] + w*1024);
    g2lds16((const char*)bB + w*1024 + l*16, (char*)&Bs[b][0] + w*1024);
  };

  stage(0, 0);
  #pragma unroll
  for(int kc=0; kc<26; ++kc){
    if(kc+1 < 26) stage(kc+1, (kc+1)&1);
    if(kc < 25) asm volatile("s_waitcnt vmcnt(2)" ::: "memory");
    else        asm volatile("s_waitcnt vmcnt(0)" ::: "memory");
    __builtin_amdgcn_s_barrier();
    __builtin_amdgcn_sched_barrier(0);
    const int cu = kc & 1;
    s16x8 av = *(const s16x8*)&As[cu][(w*16 + lr)*32 + lh*8];
    #pragma unroll
    for(int g=0; g<4; ++g){
      s16x8 bv = *(const s16x8*)&Bs[cu][(g*16 + lr)*32 + lh*8];
      acc[g] = __builtin_amdgcn_mfma_f32_16x16x32_bf16(av, bv, acc[g], 0,0,0);
    }
    if(kc < 25) __builtin_amdgcn_s_barrier();   // free buf[kc&1] for stage(kc+2)
  }

  // ---- cell update epilogue; c,h in packed tiles ----
  const float* bias = dir ? b_b : b_f;
  const int m = ms*16 + lr;                        // dir-local m in [0,512)
  const float bi = bias[m], bfv = bias[H_+m], bg = bias[2*H_+m], bo = bias[3*H_+m];
  float* cp = cpk + ((size_t)(dir*32+nt)*32 + ms)*1024;            // [64][16] f32
  u16* hop = hpk_out + ((size_t)(dir*32+nt)*16 + (ms>>1))*2048 + (ms&1)*16;
  const int n0 = nt*64;
  #pragma unroll
  for(int r=0; r<4; ++r){
    const int row = w*16 + lh*4 + r;
    float gi = acc[0][r] + bi;
    float gf = acc[1][r] + bfv;
    float gc = acc[2][r] + bg;
    float go = acc[3][r] + bo;
    float c_old = cp[row*16 + lr];
    float c2 = sigm(gf)*c_old + sigm(gi)*tanhf(gc);
    float h2 = sigm(go)*tanhf(c2);
    cp[row*16 + lr] = c2;
    if(t == TW_-1) featsbf[(size_t)(n0+row)*E_ + dir*H_ + m] = f2bf(h2);
    else           hop[row*32 + lr] = f2bf(h2);
  }
}

// ===========================================================================
// q = feats @ W_att  (one-time, bf16 MFMA, fp32 out)  [verified]
// ===========================================================================
__global__ __launch_bounds__(256) void k_qgemm(const u16* __restrict__ featsbf,
                                               const u16* __restrict__ WattT,
                                               float* __restrict__ q)
{
  const int n0 = blockIdx.x*64, j0 = blockIdx.y*64;
  __shared__ __align__(16) u16 As[64*40];
  __shared__ __align__(16) u16 Bs[64*40];
  const int tid = threadIdx.x;
  const int w = tid>>6, l = tid&63, lr = l&15, lk = (l>>4)*8;
  const int arow = tid>>2, ak8 = (tid&3)*8;

  f32x4 acc[4];
  #pragma unroll
  for(int i=0;i<4;i++) acc[i] = (f32x4){0.f,0.f,0.f,0.f};

  for(int kc=0; kc<32; ++kc){
    *(s16x8*)&As[arow*40 + ak8] = *(const s16x8*)&featsbf[(size_t)(n0+arow)*E_ + kc*32 + ak8];
    *(s16x8*)&Bs[arow*40 + ak8] = *(const s16x8*)&WattT[(size_t)(j0+arow)*E_ + kc*32 + ak8];
    __syncthreads();
    s16x8 av = *(const s16x8*)&As[(w*16 + lr)*40 + lk];
    #pragma unroll
    for(int mf=0; mf<4; ++mf){
      s16x8 bv = *(const s16x8*)&Bs[(mf*16 + lr)*40 + lk];
      acc[mf] = __builtin_amdgcn_mfma_f32_16x16x32_bf16(av, bv, acc[mf], 0,0,0);
    }
    __syncthreads();
  }
  #pragma unroll
  for(int mf=0; mf<4; ++mf)
    #pragma unroll
    for(int r=0; r<4; ++r){
      int n = n0 + w*16 + (l>>4)*4 + r;
      q[(size_t)n*E_ + j0 + mf*16 + lr] = acc[mf][r];
    }
}

// ===========================================================================
// Phase 2 building blocks (verified R11)
// ===========================================================================
struct GArg2 {
  const u16* xA; const u16* xB;
  long ldA; long ldB;
  const u16* W; int K;
};

template<int NCH>
__device__ __forceinline__ void gemm32v3(const GArg2 a, int R, int xt, int ks,
                                         int KS, int z, float* __restrict__ part,
                                         char* smem)
{
  u16* Xs = (u16*)smem;                  // NCH x [32*40]
  u16* Ws = (u16*)smem + 4*1280;         // NCH x [128*32]
  const int Kc = a.K / KS;               // = NCH*32
  const int kb0 = ks * Kc;
  const int tid = threadIdx.x;
  const int w = tid>>6, l = tid&63, lr = l&15, lh = l>>4;

  #pragma unroll
  for(int c=0;c<NCH;++c){
    const int kb = kb0 + c*32;
    #pragma unroll
    for(int c2=0;c2<2;++c2){
      const int cc = w*2 + c2;
      const char* g = (const char*)(a.W + (size_t)(xt*128 + cc*16 + (l>>2))*a.K + kb) + (l&3)*16;
      g2lds16(g, (char*)(Ws + c*4096) + cc*1024);
    }
  }
  const int row = tid>>3, k4 = (tid&7)*4;
  short4 xr[NCH];
  #pragma unroll
  for(int c=0;c<NCH;++c){
    const int kb = kb0 + c*32;
    short4 xv = *(const short4*)&a.xA[(size_t)row*a.ldA + kb + k4];
    if(a.xB){
      short4 yv = *(const short4*)&a.xB[(size_t)row*a.ldB + kb + k4];
      xv.x = (short)f2bf(bf2f((u16)xv.x)+bf2f((u16)yv.x));
      xv.y = (short)f2bf(bf2f((u16)xv.y)+bf2f((u16)yv.y));
      xv.z = (short)f2bf(bf2f((u16)xv.z)+bf2f((u16)yv.z));
      xv.w = (short)f2bf(bf2f((u16)xv.w)+bf2f((u16)yv.w));
    }
    xr[c] = xv;
  }
  #pragma unroll
  for(int c=0;c<NCH;++c)
    *(short4*)&Xs[c*1280 + row*40 + k4] = xr[c];

  asm volatile("s_waitcnt vmcnt(0) lgkmcnt(0)" ::: "memory");
  __builtin_amdgcn_s_barrier();
  __builtin_amdgcn_sched_barrier(0);

  f32x4 a00={0,0,0,0}, a01={0,0,0,0}, a10={0,0,0,0}, a11={0,0,0,0};
  #pragma unroll
  for(int c=0;c<NCH;++c){
    const u16* Xc = Xs + c*1280;
    const u16* Wc = Ws + c*4096;
    s16x8 av0 = *(const s16x8*)&Xc[lr*40 + lh*8];
    s16x8 av1 = *(const s16x8*)&Xc[(16+lr)*40 + lh*8];
    s16x8 bv0 = *(const s16x8*)&Wc[(w*32 + lr)*32 + lh*8];
    s16x8 bv1 = *(const s16x8*)&Wc[(w*32 + 16 + lr)*32 + lh*8];
    a00 = __builtin_amdgcn_mfma_f32_16x16x32_bf16(av0, bv0, a00, 0,0,0);
    a01 = __builtin_amdgcn_mfma_f32_16x16x32_bf16(av0, bv1, a01, 0,0,0);
    a10 = __builtin_amdgcn_mfma_f32_16x16x32_bf16(av1, bv0, a10, 0,0,0);
    a11 = __builtin_amdgcn_mfma_f32_16x16x32_bf16(av1, bv1, a11, 0,0,0);
  }
  float* dst = part + (size_t)((z*KS + ks)*B_)*R + xt*128 + w*32;
  f32x4 accs[2][2] = {{a00,a01},{a10,a11}};
  #pragma unroll
  for(int nf=0; nf<2; ++nf)
    #pragma unroll
    for(int mf=0; mf<2; ++mf)
      #pragma unroll
      for(int r=0; r<4; ++r){
        int n = nf*16 + lh*4 + r;
        dst[(size_t)n*R + mf*16 + lr] = accs[nf][mf][r];
      }
}

__device__ __forceinline__ void att_body(const float* __restrict__ q,
                                         const u16* __restrict__ histbf,
                                         const u16* __restrict__ featsbf,
                                         u16* __restrict__ xcbf,
                                         int i, int b, char* smem)
{
  float* qs = (float*)smem;      // 1024
  float* sc = qs + E_;           // 64
  const int tid = threadIdx.x;
  *(float4*)&qs[tid*4] = *(const float4*)&q[((size_t)b*T_ + i)*E_ + tid*4];
  __syncthreads();
  const int wv = tid>>6, ln = tid&63;
  for(int L = wv; L <= i; L += 4){
    const u16* hl = histbf + ((size_t)L*B_ + b)*E_;
    float s = 0.f;
    s16x8 h0 = *(const s16x8*)&hl[ln*16];
    s16x8 h1 = *(const s16x8*)&hl[ln*16 + 8];
    #pragma unroll
    for(int j=0;j<8;j++){
      s += qs[ln*16 + j]     * bf2f((u16)h0[j]);
      s += qs[ln*16 + 8 + j] * bf2f((u16)h1[j]);
    }
    #pragma unroll
    for(int off=32; off; off>>=1) s += __shfl_down(s, off);
    if(ln == 0) sc[L] = s;
  }
  __syncthreads();
  if(tid < 64){
    float v  = (tid <= i) ? sc[tid] : -INFINITY;
    float mx = v;
    #pragma unroll
    for(int off=32; off; off>>=1) mx = fmaxf(mx, __shfl_xor(mx, off));
    float ex = (tid <= i) ? expf(v - mx) : 0.f;
    float sm = ex;
    #pragma unroll
    for(int off=32; off; off>>=1) sm += __shfl_xor(sm, off);
    sc[tid] = ex / sm;
  }
  __syncthreads();
  const int e4 = tid*4;
  float c0=0.f, c1=0.f, c2=0.f, c3=0.f;
  for(int L=0; L<=i; ++L){
    float wl = sc[L];
    short4 hv = *(const short4*)&histbf[((size_t)L*B_ + b)*E_ + e4];
    c0 += wl*bf2f((u16)hv.x);
    c1 += wl*bf2f((u16)hv.y);
    c2 += wl*bf2f((u16)hv.z);
    c3 += wl*bf2f((u16)hv.w);
  }
  const u16* xi = featsbf + ((size_t)b*T_ + i)*E_ + e4;
  xcbf[(size_t)b*E_ + e4 + 0] = f2bf(bf2f(xi[0]) + c0);
  xcbf[(size_t)b*E_ + e4 + 1] = f2bf(bf2f(xi[1]) + c1);
  xcbf[(size_t)b*E_ + e4 + 2] = f2bf(bf2f(xi[2]) + c2);
  xcbf[(size_t)b*E_ + e4 + 3] = f2bf(bf2f(xi[3]) + c3);
}

__device__ __forceinline__ void gru_comb(const float* __restrict__ part, int R, int J, int KS,
                                         const float* __restrict__ bih, const float* __restrict__ bhh,
                                         const float* __restrict__ hprev_f,
                                         float* __restrict__ dst_f,
                                         u16* __restrict__ dstbf,
                                         float* __restrict__ dst_seq, int idx)
{
  const int b = idx / J, e = idx - b*J;
  float ir=0.f, iz=0.f, in_=0.f, hr=0.f, hz=0.f, hn=0.f;
  for(int ks=0; ks<KS; ++ks){
    const float* p0 = part + (size_t)(ks*B_ + b)*R;
    const float* p1 = part + (size_t)((KS+ks)*B_ + b)*R;
    ir += p0[e]; iz += p0[J+e]; in_ += p0[2*J+e];
    hr += p1[e]; hz += p1[J+e]; hn  += p1[2*J+e];
  }
  ir += bih[e]; iz += bih[J+e]; in_ += bih[2*J+e];
  hr += bhh[e]; hz += bhh[J+e]; hn  += bhh[2*J+e];
  const float r = sigm(ir + hr);
  const float z = sigm(iz + hz);
  const float n = tanhf(in_ + r*hn);
  const float hp = hprev_f[(size_t)b*J + e];
  const float h2 = (1.f - z)*n + z*hp;
  dst_f[(size_t)b*J + e] = h2;
  dstbf[(size_t)b*J + e] = f2bf(h2);
  if(dst_seq) dst_seq[(size_t)b*J + e] = h2;
}

// M(i): g-gemm(i) [384] | att(i) [32] | p-comb(i-1) [128] | e-comb(i-2) [64]
__global__ __launch_bounds__(256) void k_M(GArg2 g0, GArg2 g1,
    float* __restrict__ part_g,
    const float* __restrict__ q, const u16* __restrict__ histbf,
    const u16* __restrict__ featsbf, u16* __restrict__ xcbf,
    const float* __restrict__ part_p, const float* __restrict__ p_bih,
    const float* __restrict__ p_bhh, float* __restrict__ partyf_pm1,
    u16* __restrict__ partybf_pm1,
    const float* __restrict__ part_e, const float* __restrict__ e_bih,
    const float* __restrict__ e_bhh, float* __restrict__ emof,
    u16* __restrict__ emobf, float* __restrict__ emo_seq, int i)
{
  __shared__ __align__(16) char smem[43008];
  const int x = blockIdx.x;
  if(x < 384){
    if(i >= T_) return;
    const int xt = x % 24, ks = (x/24) & 7, z = x/192;
    gemm32v3<4>(z ? g1 : g0, 3*E_, xt, ks, 8, z, part_g, smem);
  } else if(x < 416){
    if(i >= T_) return;
    att_body(q, histbf, featsbf, xcbf, i, x-384, smem);
  } else if(x < 544){
    const int ip = i-1;
    if(ip < 0 || ip >= T_) return;
    gru_comb(part_p, 3*E_, E_, 8, p_bih, p_bhh, partyf_pm1, partyf_pm1,
             partybf_pm1, nullptr, (x-416)*256 + (int)threadIdx.x);
  } else {
    const int ie = i-2;
    if(ie < 0 || ie >= T_) return;
    gru_comb(part_e, 3*HH_, HH_, 8, e_bih, e_bhh, emof, emof, emobf,
             emo_seq + (size_t)ie*B_*HH_, (x-544)*256 + (int)threadIdx.x);
  }
}

// B2(i): g-comb(i) [128] | p-gemm(i) [384] | e-gemm(i-1) [192]   grid 704
__global__ __launch_bounds__(256) void k_B2(GArg2 p0, GArg2 p1, GArg2 e0, GArg2 e1,
    const float* __restrict__ part_g,
    const float* __restrict__ g_bih, const float* __restrict__ g_bhh,
    const float* __restrict__ gf_prev, float* __restrict__ gf_next,
    u16* __restrict__ histbf,
    float* __restrict__ part_p, float* __restrict__ part_e, int i)
{
  __shared__ __align__(16) char smem[43008];
  const int x = blockIdx.x;
  if(x < 128){
    if(i >= T_) return;
    gru_comb(part_g, 3*E_, E_, 8, g_bih, g_bhh, gf_prev, gf_next,
             histbf + (size_t)(i+1)*B_*E_, nullptr, x*256 + (int)threadIdx.x);
  } else if(x < 512){
    if(i >= T_) return;
    const int ix = x-128, xt = ix % 24, ks = (ix/24) & 7, z = ix/192;
    gemm32v3<4>(z ? p1 : p0, 3*E_, xt, ks, 8, z, part_p, smem);
  } else {
    if(i < 1) return;
    const int ix = x-512, xt = ix % 12, ks = (ix/12) & 7, z = ix/96;
    if(z) gemm32v3<2>(e1, 3*HH_, xt, ks, 8, 1, part_e, smem);   // K=512
    else  gemm32v3<4>(e0, 3*HH_, xt, ks, 8, 0, part_e, smem);   // K=1024
  }
}

// classifier
__global__ __launch_bounds__(256) void classify(const float* __restrict__ emo_seq,
    const float* __restrict__ clsW, const float* __restrict__ clsb, float* __restrict__ out)
{
  const int idx = blockIdx.x*256 + threadIdx.x;
  if(idx >= B_*T_*C_) return;
  const int c = idx % C_;
  const int bt = idx / C_;
  const int t = bt % T_, b = bt / T_;
  const float* e = emo_seq + (size_t)(t*B_ + b)*HH_;
  const float* w = clsW + (size_t)c*HH_;
  float s = clsb[c];
  for(int h=0; h<HH_; ++h) s += e[h]*w[h];
  out[idx] = s;
}

// ===========================================================================
extern "C" void kernel_launch(void* const* d_in, const int* in_sizes, int n_in,
                              void* d_out, int out_size, void* d_ws, size_t ws_size,
                              hipStream_t stream)
{
  const float* input  = (const float*)d_in[0];
  const float* Wih_f  = (const float*)d_in[1];
  const float* Whh_f  = (const float*)d_in[2];
  const float* b_f    = (const float*)d_in[3];
  const float* Wih_b  = (const float*)d_in[4];
  const float* Whh_b  = (const float*)d_in[5];
  const float* b_b    = (const float*)d_in[6];
  const float* W_att  = (const float*)d_in[7];
  const float* g_Wih  = (const float*)d_in[8];
  const float* g_Whh  = (const float*)d_in[9];
  const float* g_bih  = (const float*)d_in[10];
  const float* g_bhh  = (const float*)d_in[11];
  const float* p_Wih  = (const float*)d_in[12];
  const float* p_Whh  = (const float*)d_in[13];
  const float* p_bih  = (const float*)d_in[14];
  const float* p_bhh  = (const float*)d_in[15];
  const float* e_Wih  = (const float*)d_in[16];
  const float* e_Whh  = (const float*)d_in[17];
  const float* e_bih  = (const float*)d_in[18];
  const float* e_bhh  = (const float*)d_in[19];
  const float* cls_W  = (const float*)d_in[20];
  const float* cls_b  = (const float*)d_in[21];

  // ---- workspace layout ----
  char* base = (char*)d_ws;
  size_t off = 0;
  auto alloc = [&](size_t bytes)->char*{
    char* p = base + off; off += (bytes + 255) & ~(size_t)255; return p;
  };
  u16*   Wpk2    = (u16*)alloc((size_t)64*26*2048*2);       // 6.8 MB
  u16*   xpk     = (u16*)alloc((size_t)32*32*10*2048*2);    // 41.9 MB (phase1 only)
  u16*   hpkA    = (u16*)alloc((size_t)2*32*16*2048*2);     // 4.19 MB (phase1 only)
  u16*   hpkB    = (u16*)alloc((size_t)2*32*16*2048*2);     // 4.19 MB (phase1 only, adjacent)
  float* cpk     = (float*)alloc((size_t)2*32*32*1024*4);   // 8.39 MB (phase1 only)
  u16*   featsbf = (u16*)alloc((size_t)N_*E_*2);
  u16*   eWih    = (u16*)alloc((size_t)3*HH_*E_*2);
  u16*   eWhh    = (u16*)alloc((size_t)3*HH_*HH_*2);
  u16*   histbf  = (u16*)alloc((size_t)(T_+1)*B_*E_*2);
  float* gfbuf   = (float*)alloc((size_t)2*B_*E_*4);
  float* partyf  = (float*)alloc((size_t)2*B_*E_*4);
  u16*   partybf = (u16*)alloc((size_t)2*B_*E_*2);
  float* emof    = (float*)alloc((size_t)B_*HH_*4);
  u16*   emobf   = (u16*)alloc((size_t)B_*HH_*2);
  float* emo_seq = (float*)alloc((size_t)T_*B_*HH_*4);
  u16*   xcbf    = (u16*)alloc((size_t)B_*E_*2);
  float* part_p  = (float*)alloc((size_t)16*B_*3*E_*4);     // 6.29 MB
  // phase-2 buffers aliased into phase-1-only regions:
  u16*   gWih    = (u16*)((char*)xpk + 0);                  // 6.29 MB
  u16*   gWhh    = (u16*)((char*)xpk + 6291456);            // 6.29 MB
  u16*   pWih    = (u16*)((char*)xpk + 12582912);           // 6.29 MB
  u16*   pWhh    = (u16*)((char*)xpk + 18874368);           // 6.29 MB
  float* part_e  = (float*)((char*)xpk + 25165824);         // 3.15 MB
  float* q       = (float*)((char*)xpk + 28311552);         // 8.39 MB
  u16*   WattT   = (u16*)((char*)xpk + 36700160);           // 2.10 MB (ends 38.8 <= 41.9)
  float* part_g  = (float*)hpkA;                            // 6.29 MB (spans hpkA+hpkB, both dead)

  // ---- zero-init (2 big memsets + 1 fused small-state kernel) ----
  hipMemsetAsync(hpkA, 0, (size_t)2*32*16*2048*2, stream);
  hipMemsetAsync(cpk,  0, (size_t)2*32*32*1024*4, stream);
  k_init0<<<dim3((2*B_*E_+255)/256), 256, 0, stream>>>(histbf, gfbuf, partyf, partybf, emof, emobf);

  // ---- pre-pass packing (phase 1 inputs) ----
  k_pack_w<<<dim3(((size_t)64*26*2048 + 255)/256), 256, 0, stream>>>(Wih_f, Whh_f, Wih_b, Whh_b, Wpk2);
  k_pack_x<<<dim3(((size_t)32*32*10*2048 + 255)/256), 256, 0, stream>>>(input, xpk);

  // ---- Phase 1: BiLSTM, 2048 blocks (8/CU resident) per step ----
  for(int t=0; t<TW_; ++t){
    u16* hin  = (t & 1) ? hpkB : hpkA;
    u16* hout = (t & 1) ? hpkA : hpkB;
    lstm7<<<dim3(64, 32), 256, 0, stream>>>(xpk, Wpk2, b_f, b_b, hin, hout, cpk, featsbf, t);
  }

  // ---- phase-2 weight conversions (AFTER phase 1: alias xpk) — ONE launch ----
  k_prep2<<<dim3((15990784 + 255)/256), 256, 0, stream>>>(
      g_Wih, g_Whh, p_Wih, p_Whh, e_Wih, e_Whh, W_att,
      gWih, gWhh, pWih, pWhh, eWih, eWhh, WattT);

  // ---- q = feats @ W_att ----
  k_qgemm<<<dim3(32, 16), 256, 0, stream>>>(featsbf, WattT, q);

  // ---- Phase 2: 2 launches/step (M + B2), i = 0..65 ----
  for(int i=0; i<=T_+1; ++i){
    GArg2 ga0{ featsbf + (size_t)i*E_, partybf + (size_t)(i&1)*B_*E_, (long)T_*E_, (long)E_, gWih, E_ };
    GArg2 ga1{ histbf + (size_t)i*B_*E_, nullptr, (long)E_, 0, gWhh, E_ };
    k_M<<<dim3(608), 256, 0, stream>>>(ga0, ga1, part_g, q, histbf, featsbf, xcbf,
                                       part_p, p_bih, p_bhh,
                                       partyf + (size_t)((i-1)&1)*B_*E_,
                                       partybf + (size_t)((i-1)&1)*B_*E_,
                                       part_e, e_bih, e_bhh, emof, emobf, emo_seq, i);
    if(i <= T_){
      GArg2 pa0{ xcbf, nullptr, (long)E_, 0, pWih, E_ };
      GArg2 pa1{ partybf + (size_t)(i&1)*B_*E_, nullptr, (long)E_, 0, pWhh, E_ };
      GArg2 ea0{ partybf + (size_t)((i-1)&1)*B_*E_, nullptr, (long)E_, 0, eWih, E_ };
      GArg2 ea1{ emobf, nullptr, (long)HH_, 0, eWhh, HH_ };
      k_B2<<<dim3(704), 256, 0, stream>>>(pa0, pa1, ea0, ea1, part_g,
                                          g_bih, g_bhh,
                                          gfbuf + (size_t)(i&1)*B_*E_,
                                          gfbuf + (size_t)((i+1)&1)*B_*E_,
                                          histbf, part_p, part_e, i);
    }
  }

  // ---- classifier ----
  classify<<<dim3((B_*T_*C_+255)/256), 256, 0, stream>>>(emo_seq, cls_W, cls_b, (float*)d_out);
}